// Round 5
// baseline (2974.575 us; speedup 1.0000x reference)
//
#include <hip/hip_runtime.h>
#include <hip/hip_fp16.h>
#include <math.h>

#define NPIX    16384
#define NSLICES 8
#define NMODES  4
#define OBJW    512
#define LSTR    136        // padded major stride (half2 units): 136%32=8

typedef float v2f __attribute__((ext_vector_type(2)));

// ---- packed fp32 complex primitives (VOP3P) --------------------------------
__device__ __forceinline__ v2f pk_add(v2f a, v2f b) {
    v2f d; asm("v_pk_add_f32 %0, %1, %2" : "=v"(d) : "v"(a), "v"(b)); return d;
}
__device__ __forceinline__ v2f pk_sub(v2f a, v2f b) {
    v2f d; asm("v_pk_add_f32 %0, %1, %2 neg_lo:[0,1] neg_hi:[0,1]"
               : "=v"(d) : "v"(a), "v"(b)); return d;
}
__device__ __forceinline__ v2f pk_fma(v2f a, v2f b, v2f c) {
    v2f d; asm("v_pk_fma_f32 %0, %1, %2, %3" : "=v"(d) : "v"(a), "v"(b), "v"(c)); return d;
}
// d = a*b (complex)
__device__ __forceinline__ v2f pk_cmul(v2f a, v2f b) {
    v2f t, d;
    asm("v_pk_mul_f32 %0, %1, %2 op_sel:[0,0] op_sel_hi:[1,0]"
        : "=v"(t) : "v"(a), "v"(b));
    asm("v_pk_fma_f32 %0, %1, %2, %3 op_sel:[1,1,0] op_sel_hi:[0,1,1] neg_lo:[1,0,0]"
        : "=v"(d) : "v"(a), "v"(b), "v"(t));
    return d;
}
// d = a*conj(b)
__device__ __forceinline__ v2f pk_cmulc(v2f a, v2f b) {
    v2f t, d;
    asm("v_pk_mul_f32 %0, %1, %2 op_sel:[0,0] op_sel_hi:[1,0]"
        : "=v"(t) : "v"(a), "v"(b));
    asm("v_pk_fma_f32 %0, %1, %2, %3 op_sel:[1,1,0] op_sel_hi:[0,1,1] neg_hi:[1,0,0]"
        : "=v"(d) : "v"(a), "v"(b), "v"(t));
    return d;
}
// d = a * (-b.x, b.y)   [= cmul with negated real part of b]
__device__ __forceinline__ v2f pk_cmul_nx(v2f a, v2f b) {
    v2f t, d;
    asm("v_pk_mul_f32 %0, %1, %2 op_sel:[0,0] op_sel_hi:[1,0] neg_lo:[0,1] neg_hi:[0,1]"
        : "=v"(t) : "v"(a), "v"(b));
    asm("v_pk_fma_f32 %0, %1, %2, %3 op_sel:[1,1,0] op_sel_hi:[0,1,1] neg_lo:[1,0,0]"
        : "=v"(d) : "v"(a), "v"(b), "v"(t));
    return d;
}
// d = -cmul(a,b)  [= a*conj((-b.x, b.y))]
__device__ __forceinline__ v2f pk_cmulc_nx(v2f a, v2f b) {
    v2f t, d;
    asm("v_pk_mul_f32 %0, %1, %2 op_sel:[0,0] op_sel_hi:[1,0] neg_lo:[0,1] neg_hi:[0,1]"
        : "=v"(t) : "v"(a), "v"(b));
    asm("v_pk_fma_f32 %0, %1, %2, %3 op_sel:[1,1,0] op_sel_hi:[0,1,1] neg_hi:[1,0,0]"
        : "=v"(d) : "v"(a), "v"(b), "v"(t));
    return d;
}
__device__ __forceinline__ v2f pk_mnegi(v2f a) { return (v2f){a.y, -a.x}; }  // a * -i
__device__ __forceinline__ v2f pk_mposi(v2f a) { return (v2f){-a.y, a.x}; }  // a * +i

// 4-bit reversal
__host__ __device__ constexpr int BR4(int p) {
    return ((p & 1) << 3) | ((p & 2) << 1) | ((p & 4) >> 1) | ((p & 8) >> 3);
}
__host__ __device__ constexpr int BR3(int c) {
    return ((c & 1) << 2) | (c & 2) | ((c & 4) >> 2);
}

// ---- lane exchange primitives ---------------------------------------------
__device__ __forceinline__ float xor1f(float x) {
    int i = __float_as_int(x);
    return __int_as_float(__builtin_amdgcn_update_dpp(i, i, 0xB1, 0xF, 0xF, false));
}
__device__ __forceinline__ float xor2f(float x) {
    int i = __float_as_int(x);
    return __int_as_float(__builtin_amdgcn_update_dpp(i, i, 0x4E, 0xF, 0xF, false));
}
__device__ __forceinline__ float xor4f(float x) {
    return __int_as_float(__builtin_amdgcn_ds_swizzle(__float_as_int(x), 0x101F));
}

// cross-8 stage-A twiddle fA(c) = (c<4) ? 1 : W8^(c-4)
__device__ __constant__ float FA_RE[8] = {1,1,1,1, 1.0f,  0.707106781f,  0.0f, -0.707106781f};
__device__ __constant__ float FA_IM[8] = {0,0,0,0, 0.0f, -0.707106781f, -1.0f, -0.707106781f};

// ---- local 16-point FFT (packed); W-table = only W1,W2,W3 live -------------
// W[k]=e^{i 2pi k/16}; W[8-k] mirror handled by neg-modifier variants:
// fwd tw>=5: cmulc(d,W[tw]) = -cmul(d,W[8-tw]) = pk_cmulc_nx(d, W[8-tw])
// inv tw>=5: cmul(w,W[tw])  = w*(-x,y)         = pk_cmul_nx(w, W[8-tw])
__device__ __forceinline__ v2f twmulc_fwd(int tw, v2f d, v2f W1, v2f W2, v2f W3) {
    return (tw == 0) ? d
         : (tw == 4) ? pk_mnegi(d)
         : (tw == 1) ? pk_cmulc(d, W1)
         : (tw == 2) ? pk_cmulc(d, W2)
         : (tw == 3) ? pk_cmulc(d, W3)
         : (tw == 5) ? pk_cmulc_nx(d, W3)
         : (tw == 6) ? pk_cmulc_nx(d, W2)
                     : pk_cmulc_nx(d, W1);
}
__device__ __forceinline__ v2f twmul_inv(int tw, v2f w, v2f W1, v2f W2, v2f W3) {
    return (tw == 0) ? w
         : (tw == 4) ? pk_mposi(w)
         : (tw == 1) ? pk_cmul(w, W1)
         : (tw == 2) ? pk_cmul(w, W2)
         : (tw == 3) ? pk_cmul(w, W3)
         : (tw == 5) ? pk_cmul_nx(w, W3)
         : (tw == 6) ? pk_cmul_nx(w, W2)
                     : pk_cmul_nx(w, W1);
}
__device__ __forceinline__ void fft16_fwd(v2f v[16], v2f W1, v2f W2, v2f W3) {
    #pragma unroll
    for (int s = 8; s >= 1; s >>= 1) {
        #pragma unroll
        for (int q = 0; q < 16; q += 2 * s) {
            #pragma unroll
            for (int j = 0; j < s; j++) {
                const int tw = j * (8 / s);
                v2f u = v[q + j], w = v[q + j + s];
                v[q + j] = pk_add(u, w);
                v2f d = pk_sub(u, w);
                v[q + j + s] = twmulc_fwd(tw, d, W1, W2, W3);
            }
        }
    }
}
__device__ __forceinline__ void fft16_inv(v2f v[16], v2f W1, v2f W2, v2f W3) {
    #pragma unroll
    for (int s = 1; s <= 8; s <<= 1) {
        #pragma unroll
        for (int q = 0; q < 16; q += 2 * s) {
            #pragma unroll
            for (int j = 0; j < s; j++) {
                const int tw = j * (8 / s);
                v2f u = v[q + j], w = v[q + j + s];
                v2f tv = twmul_inv(tw, w, W1, W2, W3);
                v[q + j]     = pk_add(u, tv);
                v[q + j + s] = pk_sub(u, tv);
            }
        }
    }
}

// ---- cross-thread DFT8 over sub-index c (xor 4,2,1) ------------------------
__device__ __forceinline__ void cross8_fwd(v2f v[16], v2f sAp, v2f sBp, v2f sCp,
                                           v2f fA, v2f rrf) {
    #pragma unroll
    for (int p = 0; p < 16; p++) {
        v2f o;
        o.x = xor4f(v[p].x); o.y = xor4f(v[p].y);
        v2f a = pk_fma(sAp, v[p], o);
        v2f b = pk_cmul(a, fA);
        o.x = xor2f(b.x); o.y = xor2f(b.y);
        v2f n = pk_fma(sBp, b, o);
        v2f r = pk_cmul(n, rrf);
        o.x = xor1f(r.x); o.y = xor1f(r.y);
        v[p] = pk_fma(sCp, r, o);
    }
}
__device__ __forceinline__ void cross8_inv(v2f v[16], v2f sAp, v2f sBp, v2f sCp,
                                           v2f fA, v2f rrf) {
    #pragma unroll
    for (int p = 0; p < 16; p++) {
        v2f o;
        o.x = xor1f(v[p].x); o.y = xor1f(v[p].y);
        v2f n = pk_fma(sCp, v[p], o);
        v2f r = pk_cmulc(n, rrf);
        o.x = xor2f(r.x); o.y = xor2f(r.y);
        v2f b = pk_fma(sBp, r, o);
        v2f a = pk_cmulc(b, fA);
        o.x = xor4f(a.x); o.y = xor4f(a.y);
        v[p] = pk_fma(sAp, a, o);
    }
}

// ---- pass A (local-first) / pass B (cross-first) ---------------------------
__device__ __forceinline__ void pass_A_fwd(v2f v[16], int c, v2f sAp, v2f sBp,
                                           v2f sCp, v2f fA, v2f rrf,
                                           v2f W1, v2f W2, v2f W3, const v2f* tA) {
    fft16_fwd(v, W1, W2, W3);
    #pragma unroll
    for (int p = 0; p < 16; p++) v[p] = pk_cmul(v[p], tA[8 * p + c]);
    cross8_fwd(v, sAp, sBp, sCp, fA, rrf);
}
__device__ __forceinline__ void pass_A_inv(v2f v[16], int c, v2f sAp, v2f sBp,
                                           v2f sCp, v2f fA, v2f rrf,
                                           v2f W1, v2f W2, v2f W3, const v2f* tA) {
    cross8_inv(v, sAp, sBp, sCp, fA, rrf);
    #pragma unroll
    for (int p = 0; p < 16; p++) v[p] = pk_cmulc(v[p], tA[8 * p + c]);
    fft16_inv(v, W1, W2, W3);
}
__device__ __forceinline__ void pass_B_fwd(v2f v[16], int c, v2f sAp, v2f sBp,
                                           v2f sCp, v2f fA, v2f rrf,
                                           v2f W1, v2f W2, v2f W3, const v2f* tB) {
    cross8_fwd(v, sAp, sBp, sCp, fA, rrf);
    #pragma unroll
    for (int i = 0; i < 16; i++) v[i] = pk_cmul(v[i], tB[8 * i + c]);
    fft16_fwd(v, W1, W2, W3);
}
__device__ __forceinline__ void pass_B_inv(v2f v[16], int c, v2f sAp, v2f sBp,
                                           v2f sCp, v2f fA, v2f rrf,
                                           v2f W1, v2f W2, v2f W3, const v2f* tB) {
    fft16_inv(v, W1, W2, W3);
    #pragma unroll
    for (int i = 0; i < 16; i++) v[i] = pk_cmulc(v[i], tB[8 * i + c]);
    cross8_inv(v, sAp, sBp, sCp, fA, rrf);
}

// ---- conversions -----------------------------------------------------------
__device__ __forceinline__ __half2 toh2(v2f a) {
    return __float22half2_rn(make_float2(a.x, a.y));
}
__device__ __forceinline__ v2f frh2(__half2 h) {
    float2 f = __half22float2(h);
    return (v2f){f.x, f.y};
}

#define W1C (v2f){0.923879533f, 0.382683432f}
#define W2C (v2f){0.707106781f, 0.707106781f}
#define W3C (v2f){0.382683432f, 0.923879533f}

// ============================================================================
// Kernel A: 512 threads, 2 rows/thread. Needs ~112 VGPRs -> only usable if
// the backend grants a >64 budget (waves_per_eu(2) min-only). Host checks
// localSizeBytes and falls back to kernel B if this spilled.
// ============================================================================
__global__ void
__attribute__((amdgpu_flat_work_group_size(512, 512)))
__attribute__((amdgpu_waves_per_eu(2)))
multislice_2row(const float* __restrict__ probe_re,
                const float* __restrict__ probe_im,
                const float* __restrict__ obj_re,
                const float* __restrict__ obj_im,
                const int*   __restrict__ positions,
                float*       __restrict__ out)
{
    __shared__ __half2 LTH[128 * LSTR];
    __shared__ v2f     tA[128];
    __shared__ v2f     tB[128];
    __shared__ v2f     pytp[128];

    const int t  = threadIdx.x;
    const int g0 = t >> 3;
    const int c  = t & 7;
    const int rc = BR3(c);
    const int ga = g0, gb = g0 + 64;
    const int gha = ga >> 4, ghb = gb >> 4;
    const int rho_a = ((ga & 15) << 3) | gha;
    const int rho_b = ((gb & 15) << 3) | ghb;
    const int n  = blockIdx.x;
    const int Y0 = positions[2 * n];
    const int X0 = positions[2 * n + 1];

    if (t < 128) {
        int p_ = t >> 3, c_ = t & 7;
        float angA = -2.0f * 3.14159265358979323846f * (float)(c_ * BR4(p_)) / 128.0f;
        float s, cc; __sincosf(angA, &s, &cc);
        tA[t] = (v2f){cc, s};
        float angB = -2.0f * 3.14159265358979323846f * (float)(p_ * BR3(c_)) / 128.0f;
        __sincosf(angB, &s, &cc);
        tB[t] = (v2f){cc, s};
        int kh = BR3(c_) + 8 * BR4(p_);
        float fy = (float)(kh < 64 ? kh : kh - 128) * (1.0f / 25.6f);
        float ph = -0.15707963267948966f * fy * fy;
        float ps, pcs; __sincosf(ph, &ps, &pcs);
        pytp[t] = (v2f){pcs * (1.0f / 16384.0f), ps * (1.0f / 16384.0f)};
    }

    const float sA = (c < 4) ? 1.0f : -1.0f;
    const float sB = (c & 2) ? -1.0f : 1.0f;
    const float sC = (c & 1) ? -1.0f : 1.0f;
    const v2f sAp = {sA, sA}, sBp = {sB, sB}, sCp = {sC, sC};
    const v2f fA  = {FA_RE[c], FA_IM[c]};
    const v2f rrf = ((c & 3) == 3) ? (v2f){0.0f, -1.0f} : (v2f){1.0f, 0.0f};
    const v2f W1 = W1C, W2 = W2C, W3 = W3C;

    float fxa = (float)(ga < 64 ? ga : ga - 128) * (1.0f / 25.6f);
    float pha = -0.15707963267948966f * fxa * fxa;
    float pxs, pxc; __sincosf(pha, &pxs, &pxc);
    const v2f px_a = {pxc, pxs};
    float fxb = (float)(gb < 64 ? gb : gb - 128) * (1.0f / 25.6f);
    float phb = -0.15707963267948966f * fxb * fxb;
    __sincosf(phb, &pxs, &pxc);
    const v2f px_b = {pxc, pxs};
    __syncthreads();

    const long long base = (long long)n * NPIX;
    const int a1w_a = rho_a ^ rc;
    const int a1w_b = rho_b ^ rc;
    const int a1r_a = ga * LSTR + (c ^ gha);
    const int a1r_b = gb * LSTR + (c ^ ghb);
    const int a2w_a = rho_a ^ c;
    const int a2w_b = rho_b ^ c;
    const int a2r_a = ga * LSTR + (rc ^ gha);
    const int a2r_b = gb * LSTR + (rc ^ ghb);

    v2f va[16], vb[16];

    for (int m = 0; m < NMODES; m++) {
        __syncthreads();
        #pragma unroll
        for (int i = 0; i < 16; i++) {
            int w  = c + 8 * i;
            int pia = m * NPIX + ga * 128 + w;
            v2f pra = {probe_re[pia], probe_im[pia]};
            int oia = (Y0 + ga) * OBJW + X0 + w;
            v2f oba = {obj_re[oia], obj_im[oia]};
            va[i] = pk_cmul(pra, oba);
            int pib = m * NPIX + gb * 128 + w;
            v2f prb = {probe_re[pib], probe_im[pib]};
            int oib = (Y0 + gb) * OBJW + X0 + w;
            v2f obb = {obj_re[oib], obj_im[oib]};
            vb[i] = pk_cmul(prb, obb);
        }

        for (int s = 1; s < NSLICES; s++) {
            pass_A_fwd(va, c, sAp, sBp, sCp, fA, rrf, W1, W2, W3, tA);
            pass_A_fwd(vb, c, sAp, sBp, sCp, fA, rrf, W1, W2, W3, tA);
            #pragma unroll
            for (int p = 0; p < 16; p++) {
                int kw = BR4(p) + 16 * rc;
                LTH[kw * LSTR + a1w_a] = toh2(va[p]);
                LTH[kw * LSTR + a1w_b] = toh2(vb[p]);
            }
            __syncthreads();
            #pragma unroll
            for (int i = 0; i < 16; i++) {
                va[i] = frh2(LTH[a1r_a + 8 * i]);
                vb[i] = frh2(LTH[a1r_b + 8 * i]);
            }
            __syncthreads();
            pass_B_fwd(va, c, sAp, sBp, sCp, fA, rrf, W1, W2, W3, tB);
            pass_B_fwd(vb, c, sAp, sBp, sCp, fA, rrf, W1, W2, W3, tB);
            #pragma unroll
            for (int p = 0; p < 16; p++) {
                v2f py = pytp[8 * p + c];
                va[p] = pk_cmul(va[p], pk_cmul(py, px_a));
                vb[p] = pk_cmul(vb[p], pk_cmul(py, px_b));
            }
            pass_B_inv(va, c, sAp, sBp, sCp, fA, rrf, W1, W2, W3, tB);
            pass_B_inv(vb, c, sAp, sBp, sCp, fA, rrf, W1, W2, W3, tB);
            #pragma unroll
            for (int i = 0; i < 16; i++) {
                LTH[(i + 16 * c) * LSTR + a2w_a] = toh2(va[i]);
                LTH[(i + 16 * c) * LSTR + a2w_b] = toh2(vb[i]);
            }
            __syncthreads();
            #pragma unroll
            for (int p = 0; p < 16; p++) {
                va[p] = frh2(LTH[a2r_a + 8 * BR4(p)]);
                vb[p] = frh2(LTH[a2r_b + 8 * BR4(p)]);
            }
            __syncthreads();
            pass_A_inv(va, c, sAp, sBp, sCp, fA, rrf, W1, W2, W3, tA);
            pass_A_inv(vb, c, sAp, sBp, sCp, fA, rrf, W1, W2, W3, tA);
            #pragma unroll
            for (int i = 0; i < 16; i++) {
                int w  = c + 8 * i;
                int oia = (s * OBJW + Y0 + ga) * OBJW + X0 + w;
                v2f oba = {obj_re[oia], obj_im[oia]};
                va[i] = pk_cmul(va[i], oba);
                int oib = (s * OBJW + Y0 + gb) * OBJW + X0 + w;
                v2f obb = {obj_re[oib], obj_im[oib]};
                vb[i] = pk_cmul(vb[i], obb);
            }
        }

        pass_A_fwd(va, c, sAp, sBp, sCp, fA, rrf, W1, W2, W3, tA);
        pass_A_fwd(vb, c, sAp, sBp, sCp, fA, rrf, W1, W2, W3, tA);
        #pragma unroll
        for (int p = 0; p < 16; p++) {
            int kw = BR4(p) + 16 * rc;
            LTH[kw * LSTR + a1w_a] = toh2(va[p]);
            LTH[kw * LSTR + a1w_b] = toh2(vb[p]);
        }
        __syncthreads();
        #pragma unroll
        for (int i = 0; i < 16; i++) {
            va[i] = frh2(LTH[a1r_a + 8 * i]);
            vb[i] = frh2(LTH[a1r_b + 8 * i]);
        }
        pass_B_fwd(va, c, sAp, sBp, sCp, fA, rrf, W1, W2, W3, tB);
        pass_B_fwd(vb, c, sAp, sBp, sCp, fA, rrf, W1, W2, W3, tB);
        #pragma unroll
        for (int p = 0; p < 16; p++) {
            int kh = BR3(c) + 8 * BR4(p);
            long long oia = base + (long long)(((kh ^ 64) << 7) + (ga ^ 64));
            float vala = fmaf(va[p].x, va[p].x, va[p].y * va[p].y);
            if (m > 0) vala += out[oia];
            out[oia] = vala;
            long long oib = base + (long long)(((kh ^ 64) << 7) + (gb ^ 64));
            float valb = fmaf(vb[p].x, vb[p].x, vb[p].y * vb[p].y);
            if (m > 0) valb += out[oib];
            out[oib] = valb;
        }
    }
}

// ============================================================================
// Kernel B: round-2 structure (1024 threads, 1 row/thread). Proven 1224 us.
// ============================================================================
__global__ void
__attribute__((amdgpu_flat_work_group_size(1024, 1024)))
multislice_1row(const float* __restrict__ probe_re,
                const float* __restrict__ probe_im,
                const float* __restrict__ obj_re,
                const float* __restrict__ obj_im,
                const int*   __restrict__ positions,
                float*       __restrict__ out)
{
    __shared__ __half2 LTH[128 * LSTR];
    __shared__ v2f     tA[128];
    __shared__ v2f     tB[128];
    __shared__ v2f     pytp[128];

    const int t  = threadIdx.x;
    const int g  = t >> 3;
    const int c  = t & 7;
    const int rc = BR3(c);
    const int gh = g >> 4;
    const int rho_g = ((g & 15) << 3) | gh;
    const int n  = blockIdx.x;
    const int Y0 = positions[2 * n];
    const int X0 = positions[2 * n + 1];

    if (t < 128) {
        int p_ = t >> 3, c_ = t & 7;
        float angA = -2.0f * 3.14159265358979323846f * (float)(c_ * BR4(p_)) / 128.0f;
        float s, cc; __sincosf(angA, &s, &cc);
        tA[t] = (v2f){cc, s};
        float angB = -2.0f * 3.14159265358979323846f * (float)(p_ * BR3(c_)) / 128.0f;
        __sincosf(angB, &s, &cc);
        tB[t] = (v2f){cc, s};
        int kh = BR3(c_) + 8 * BR4(p_);
        float fy = (float)(kh < 64 ? kh : kh - 128) * (1.0f / 25.6f);
        float ph = -0.15707963267948966f * fy * fy;
        float ps, pcs; __sincosf(ph, &ps, &pcs);
        pytp[t] = (v2f){pcs * (1.0f / 16384.0f), ps * (1.0f / 16384.0f)};
    }

    const float sA = (c < 4) ? 1.0f : -1.0f;
    const float sB = (c & 2) ? -1.0f : 1.0f;
    const float sC = (c & 1) ? -1.0f : 1.0f;
    const v2f sAp = {sA, sA}, sBp = {sB, sB}, sCp = {sC, sC};
    const v2f fA  = {FA_RE[c], FA_IM[c]};
    const v2f rrf = ((c & 3) == 3) ? (v2f){0.0f, -1.0f} : (v2f){1.0f, 0.0f};
    const v2f W1 = W1C, W2 = W2C, W3 = W3C;

    float fx = (float)(g < 64 ? g : g - 128) * (1.0f / 25.6f);
    float phx = -0.15707963267948966f * fx * fx;
    float pxs, pxc; __sincosf(phx, &pxs, &pxc);
    const v2f px = {pxc, pxs};
    __syncthreads();

    const long long base = (long long)n * NPIX;
    const int a1w = rho_g ^ rc;
    const int a1r = g * LSTR + (c ^ gh);
    const int a2w = rho_g ^ c;
    const int a2r = g * LSTR + (rc ^ gh);

    v2f v[16];

    for (int m = 0; m < NMODES; m++) {
        __syncthreads();
        #pragma unroll
        for (int i = 0; i < 16; i++) {
            int w  = c + 8 * i;
            int pi = m * NPIX + g * 128 + w;
            v2f pr = {probe_re[pi], probe_im[pi]};
            int oi = (Y0 + g) * OBJW + X0 + w;
            v2f ob = {obj_re[oi], obj_im[oi]};
            v[i] = pk_cmul(pr, ob);
        }

        for (int s = 1; s < NSLICES; s++) {
            pass_A_fwd(v, c, sAp, sBp, sCp, fA, rrf, W1, W2, W3, tA);
            #pragma unroll
            for (int p = 0; p < 16; p++) {
                int kw = BR4(p) + 16 * rc;
                LTH[kw * LSTR + a1w] = toh2(v[p]);
            }
            __syncthreads();
            #pragma unroll
            for (int i = 0; i < 16; i++)
                v[i] = frh2(LTH[a1r + 8 * i]);
            __syncthreads();
            pass_B_fwd(v, c, sAp, sBp, sCp, fA, rrf, W1, W2, W3, tB);
            #pragma unroll
            for (int p = 0; p < 16; p++) {
                v2f pp = pk_cmul(pytp[8 * p + c], px);
                v[p] = pk_cmul(v[p], pp);
            }
            pass_B_inv(v, c, sAp, sBp, sCp, fA, rrf, W1, W2, W3, tB);
            #pragma unroll
            for (int i = 0; i < 16; i++)
                LTH[(i + 16 * c) * LSTR + a2w] = toh2(v[i]);
            __syncthreads();
            #pragma unroll
            for (int p = 0; p < 16; p++)
                v[p] = frh2(LTH[a2r + 8 * BR4(p)]);
            __syncthreads();
            pass_A_inv(v, c, sAp, sBp, sCp, fA, rrf, W1, W2, W3, tA);
            #pragma unroll
            for (int i = 0; i < 16; i++) {
                int w  = c + 8 * i;
                int oi = (s * OBJW + Y0 + g) * OBJW + X0 + w;
                v2f ob = {obj_re[oi], obj_im[oi]};
                v[i] = pk_cmul(v[i], ob);
            }
        }

        pass_A_fwd(v, c, sAp, sBp, sCp, fA, rrf, W1, W2, W3, tA);
        #pragma unroll
        for (int p = 0; p < 16; p++) {
            int kw = BR4(p) + 16 * rc;
            LTH[kw * LSTR + a1w] = toh2(v[p]);
        }
        __syncthreads();
        #pragma unroll
        for (int i = 0; i < 16; i++)
            v[i] = frh2(LTH[a1r + 8 * i]);
        pass_B_fwd(v, c, sAp, sBp, sCp, fA, rrf, W1, W2, W3, tB);
        #pragma unroll
        for (int p = 0; p < 16; p++) {
            int kh = BR3(c) + 8 * BR4(p);
            long long oidx = base + (long long)(((kh ^ 64) << 7) + (g ^ 64));
            float val = fmaf(v[p].x, v[p].x, v[p].y * v[p].y);
            if (m > 0) val += out[oidx];
            out[oidx] = val;
        }
    }
}

extern "C" void kernel_launch(void* const* d_in, const int* in_sizes, int n_in,
                              void* d_out, int out_size, void* d_ws, size_t ws_size,
                              hipStream_t stream) {
    const float* probe_re = (const float*)d_in[0];
    const float* probe_im = (const float*)d_in[1];
    const float* obj_re   = (const float*)d_in[2];
    const float* obj_im   = (const float*)d_in[3];
    const int*   pos      = (const int*)d_in[4];
    float* out = (float*)d_out;

    const int N = out_size / NPIX;   // 512 positions

    // Adaptive: use the 2-row kernel only if it compiled without scratch
    // (spill). Host-side query, graph-capture safe.
    static int use2row = -1;
    if (use2row < 0) {
        hipFuncAttributes fa;
        if (hipFuncGetAttributes(&fa, (const void*)multislice_2row) == hipSuccess)
            use2row = (fa.localSizeBytes < 16) ? 1 : 0;
        else
            use2row = 0;
    }

    if (use2row) {
        multislice_2row<<<dim3(N), dim3(512), 0, stream>>>(
            probe_re, probe_im, obj_re, obj_im, pos, out);
    } else {
        multislice_1row<<<dim3(N), dim3(1024), 0, stream>>>(
            probe_re, probe_im, obj_re, obj_im, pos, out);
    }
}

// Round 6
// 2397.680 us; speedup vs baseline: 1.2406x; 1.2406x over previous
//
#include <hip/hip_runtime.h>
#include <hip/hip_fp16.h>
#include <math.h>

#define NT      1024
#define NPIX    16384
#define NSLICES 8
#define NMODES  4
#define OBJW    512
#define LSTR    136        // padded major stride (half2 units): 136%32=8
#define BUF1    (128 * LSTR)   // second transpose buffer offset (half2 units)

typedef float v2f __attribute__((ext_vector_type(2)));

// ---- packed fp32 complex primitives (VOP3P) --------------------------------
__device__ __forceinline__ v2f pk_add(v2f a, v2f b) {
    v2f d; asm("v_pk_add_f32 %0, %1, %2" : "=v"(d) : "v"(a), "v"(b)); return d;
}
__device__ __forceinline__ v2f pk_sub(v2f a, v2f b) {
    v2f d; asm("v_pk_add_f32 %0, %1, %2 neg_lo:[0,1] neg_hi:[0,1]"
               : "=v"(d) : "v"(a), "v"(b)); return d;
}
__device__ __forceinline__ v2f pk_fma(v2f a, v2f b, v2f c) {
    v2f d; asm("v_pk_fma_f32 %0, %1, %2, %3" : "=v"(d) : "v"(a), "v"(b), "v"(c)); return d;
}
// d = a*b (complex)
__device__ __forceinline__ v2f pk_cmul(v2f a, v2f b) {
    v2f t, d;
    asm("v_pk_mul_f32 %0, %1, %2 op_sel:[0,0] op_sel_hi:[1,0]"
        : "=v"(t) : "v"(a), "v"(b));
    asm("v_pk_fma_f32 %0, %1, %2, %3 op_sel:[1,1,0] op_sel_hi:[0,1,1] neg_lo:[1,0,0]"
        : "=v"(d) : "v"(a), "v"(b), "v"(t));
    return d;
}
// d = a*conj(b)
__device__ __forceinline__ v2f pk_cmulc(v2f a, v2f b) {
    v2f t, d;
    asm("v_pk_mul_f32 %0, %1, %2 op_sel:[0,0] op_sel_hi:[1,0]"
        : "=v"(t) : "v"(a), "v"(b));
    asm("v_pk_fma_f32 %0, %1, %2, %3 op_sel:[1,1,0] op_sel_hi:[0,1,1] neg_hi:[1,0,0]"
        : "=v"(d) : "v"(a), "v"(b), "v"(t));
    return d;
}
// d = a * (-b.x, b.y)
__device__ __forceinline__ v2f pk_cmul_nx(v2f a, v2f b) {
    v2f t, d;
    asm("v_pk_mul_f32 %0, %1, %2 op_sel:[0,0] op_sel_hi:[1,0] neg_lo:[0,1] neg_hi:[0,1]"
        : "=v"(t) : "v"(a), "v"(b));
    asm("v_pk_fma_f32 %0, %1, %2, %3 op_sel:[1,1,0] op_sel_hi:[0,1,1] neg_lo:[1,0,0]"
        : "=v"(d) : "v"(a), "v"(b), "v"(t));
    return d;
}
// d = -cmul(a,b)
__device__ __forceinline__ v2f pk_cmulc_nx(v2f a, v2f b) {
    v2f t, d;
    asm("v_pk_mul_f32 %0, %1, %2 op_sel:[0,0] op_sel_hi:[1,0] neg_lo:[0,1] neg_hi:[0,1]"
        : "=v"(t) : "v"(a), "v"(b));
    asm("v_pk_fma_f32 %0, %1, %2, %3 op_sel:[1,1,0] op_sel_hi:[0,1,1] neg_hi:[1,0,0]"
        : "=v"(d) : "v"(a), "v"(b), "v"(t));
    return d;
}
__device__ __forceinline__ v2f pk_mnegi(v2f a) { return (v2f){a.y, -a.x}; }
__device__ __forceinline__ v2f pk_mposi(v2f a) { return (v2f){-a.y, a.x}; }

// 4-bit reversal
__host__ __device__ constexpr int BR4(int p) {
    return ((p & 1) << 3) | ((p & 2) << 1) | ((p & 4) >> 1) | ((p & 8) >> 3);
}
__host__ __device__ constexpr int BR3(int c) {
    return ((c & 1) << 2) | (c & 2) | ((c & 4) >> 2);
}

// ---- lane exchange primitives ---------------------------------------------
__device__ __forceinline__ float xor1f(float x) {
    int i = __float_as_int(x);
    return __int_as_float(__builtin_amdgcn_update_dpp(i, i, 0xB1, 0xF, 0xF, false));
}
__device__ __forceinline__ float xor2f(float x) {
    int i = __float_as_int(x);
    return __int_as_float(__builtin_amdgcn_update_dpp(i, i, 0x4E, 0xF, 0xF, false));
}
__device__ __forceinline__ float xor4f(float x) {
    return __int_as_float(__builtin_amdgcn_ds_swizzle(__float_as_int(x), 0x101F));
}

// cross-8 stage-A twiddle fA(c) = (c<4) ? 1 : W8^(c-4)
__device__ __constant__ float FA_RE[8] = {1,1,1,1, 1.0f,  0.707106781f,  0.0f, -0.707106781f};
__device__ __constant__ float FA_IM[8] = {0,0,0,0, 0.0f, -0.707106781f, -1.0f, -0.707106781f};

// ---- local 16-point FFT (packed); W-table = only W1,W2,W3 live -------------
__device__ __forceinline__ v2f twmulc_fwd(int tw, v2f d, v2f W1, v2f W2, v2f W3) {
    return (tw == 0) ? d
         : (tw == 4) ? pk_mnegi(d)
         : (tw == 1) ? pk_cmulc(d, W1)
         : (tw == 2) ? pk_cmulc(d, W2)
         : (tw == 3) ? pk_cmulc(d, W3)
         : (tw == 5) ? pk_cmulc_nx(d, W3)
         : (tw == 6) ? pk_cmulc_nx(d, W2)
                     : pk_cmulc_nx(d, W1);
}
__device__ __forceinline__ v2f twmul_inv(int tw, v2f w, v2f W1, v2f W2, v2f W3) {
    return (tw == 0) ? w
         : (tw == 4) ? pk_mposi(w)
         : (tw == 1) ? pk_cmul(w, W1)
         : (tw == 2) ? pk_cmul(w, W2)
         : (tw == 3) ? pk_cmul(w, W3)
         : (tw == 5) ? pk_cmul_nx(w, W3)
         : (tw == 6) ? pk_cmul_nx(w, W2)
                     : pk_cmul_nx(w, W1);
}
__device__ __forceinline__ void fft16_fwd(v2f v[16], v2f W1, v2f W2, v2f W3) {
    #pragma unroll
    for (int s = 8; s >= 1; s >>= 1) {
        #pragma unroll
        for (int q = 0; q < 16; q += 2 * s) {
            #pragma unroll
            for (int j = 0; j < s; j++) {
                const int tw = j * (8 / s);
                v2f u = v[q + j], w = v[q + j + s];
                v[q + j] = pk_add(u, w);
                v2f d = pk_sub(u, w);
                v[q + j + s] = twmulc_fwd(tw, d, W1, W2, W3);
            }
        }
    }
}
__device__ __forceinline__ void fft16_inv(v2f v[16], v2f W1, v2f W2, v2f W3) {
    #pragma unroll
    for (int s = 1; s <= 8; s <<= 1) {
        #pragma unroll
        for (int q = 0; q < 16; q += 2 * s) {
            #pragma unroll
            for (int j = 0; j < s; j++) {
                const int tw = j * (8 / s);
                v2f u = v[q + j], w = v[q + j + s];
                v2f tv = twmul_inv(tw, w, W1, W2, W3);
                v[q + j]     = pk_add(u, tv);
                v[q + j + s] = pk_sub(u, tv);
            }
        }
    }
}

// ---- cross-thread DFT8 over sub-index c (xor 4,2,1) ------------------------
__device__ __forceinline__ void cross8_fwd(v2f v[16], v2f sAp, v2f sBp, v2f sCp,
                                           v2f fA, v2f rrf) {
    #pragma unroll
    for (int p = 0; p < 16; p++) {
        v2f o;
        o.x = xor4f(v[p].x); o.y = xor4f(v[p].y);
        v2f a = pk_fma(sAp, v[p], o);
        v2f b = pk_cmul(a, fA);
        o.x = xor2f(b.x); o.y = xor2f(b.y);
        v2f n = pk_fma(sBp, b, o);
        v2f r = pk_cmul(n, rrf);
        o.x = xor1f(r.x); o.y = xor1f(r.y);
        v[p] = pk_fma(sCp, r, o);
    }
}
__device__ __forceinline__ void cross8_inv(v2f v[16], v2f sAp, v2f sBp, v2f sCp,
                                           v2f fA, v2f rrf) {
    #pragma unroll
    for (int p = 0; p < 16; p++) {
        v2f o;
        o.x = xor1f(v[p].x); o.y = xor1f(v[p].y);
        v2f n = pk_fma(sCp, v[p], o);
        v2f r = pk_cmulc(n, rrf);
        o.x = xor2f(r.x); o.y = xor2f(r.y);
        v2f b = pk_fma(sBp, r, o);
        v2f a = pk_cmulc(b, fA);
        o.x = xor4f(a.x); o.y = xor4f(a.y);
        v[p] = pk_fma(sAp, a, o);
    }
}

// ---- pass A (local-first) / pass B (cross-first) ---------------------------
__device__ __forceinline__ void pass_A_fwd(v2f v[16], int c, v2f sAp, v2f sBp,
                                           v2f sCp, v2f fA, v2f rrf,
                                           v2f W1, v2f W2, v2f W3, const v2f* tA) {
    fft16_fwd(v, W1, W2, W3);
    #pragma unroll
    for (int p = 0; p < 16; p++) v[p] = pk_cmul(v[p], tA[8 * p + c]);
    cross8_fwd(v, sAp, sBp, sCp, fA, rrf);
}
__device__ __forceinline__ void pass_A_inv(v2f v[16], int c, v2f sAp, v2f sBp,
                                           v2f sCp, v2f fA, v2f rrf,
                                           v2f W1, v2f W2, v2f W3, const v2f* tA) {
    cross8_inv(v, sAp, sBp, sCp, fA, rrf);
    #pragma unroll
    for (int p = 0; p < 16; p++) v[p] = pk_cmulc(v[p], tA[8 * p + c]);
    fft16_inv(v, W1, W2, W3);
}
__device__ __forceinline__ void pass_B_fwd(v2f v[16], int c, v2f sAp, v2f sBp,
                                           v2f sCp, v2f fA, v2f rrf,
                                           v2f W1, v2f W2, v2f W3, const v2f* tB) {
    cross8_fwd(v, sAp, sBp, sCp, fA, rrf);
    #pragma unroll
    for (int i = 0; i < 16; i++) v[i] = pk_cmul(v[i], tB[8 * i + c]);
    fft16_fwd(v, W1, W2, W3);
}
__device__ __forceinline__ void pass_B_inv(v2f v[16], int c, v2f sAp, v2f sBp,
                                           v2f sCp, v2f fA, v2f rrf,
                                           v2f W1, v2f W2, v2f W3, const v2f* tB) {
    fft16_inv(v, W1, W2, W3);
    #pragma unroll
    for (int i = 0; i < 16; i++) v[i] = pk_cmulc(v[i], tB[8 * i + c]);
    cross8_inv(v, sAp, sBp, sCp, fA, rrf);
}

// ---- conversions -----------------------------------------------------------
__device__ __forceinline__ __half2 toh2(v2f a) {
    return __float22half2_rn(make_float2(a.x, a.y));
}
__device__ __forceinline__ v2f frh2(__half2 h) {
    float2 f = __half22float2(h);
    return (v2f){f.x, f.y};
}

#define W1C (v2f){0.923879533f, 0.382683432f}
#define W2C (v2f){0.707106781f, 0.707106781f}
#define W3C (v2f){0.382683432f, 0.923879533f}

// ---- main kernel: 1024 threads, 1 row/thread, DOUBLE-BUFFERED transpose ----
// T1 -> BUF0, T2 -> BUF1: the WAR guard between a buffer's read and its next
// write is provided by the *other* transpose's barrier, so each transpose
// needs only ONE __syncthreads (write->bar->read). 2 bars/slice instead of 4.
// LDS = 2x69.6KB + 3KB tables = 142KB (1 WG/CU -- which was already the case).
__global__ void
__attribute__((amdgpu_flat_work_group_size(1024, 1024)))
multislice_kernel(const float* __restrict__ probe_re,
                  const float* __restrict__ probe_im,
                  const float* __restrict__ obj_re,
                  const float* __restrict__ obj_im,
                  const int*   __restrict__ positions,
                  float*       __restrict__ out)
{
    __shared__ __half2 LTH[2 * 128 * LSTR];   // 139264 B: BUF0 (T1) + BUF1 (T2)
    __shared__ v2f     tA[128];
    __shared__ v2f     tB[128];
    __shared__ v2f     pytp[128];

    const int t  = threadIdx.x;
    const int g  = t >> 3;
    const int c  = t & 7;
    const int rc = BR3(c);
    const int gh = g >> 4;
    const int rho_g = ((g & 15) << 3) | gh;
    const int n  = blockIdx.x;
    const int Y0 = positions[2 * n];
    const int X0 = positions[2 * n + 1];

    if (t < 128) {
        int p_ = t >> 3, c_ = t & 7;
        float angA = -2.0f * 3.14159265358979323846f * (float)(c_ * BR4(p_)) / 128.0f;
        float s, cc; __sincosf(angA, &s, &cc);
        tA[t] = (v2f){cc, s};
        float angB = -2.0f * 3.14159265358979323846f * (float)(p_ * BR3(c_)) / 128.0f;
        __sincosf(angB, &s, &cc);
        tB[t] = (v2f){cc, s};
        int kh = BR3(c_) + 8 * BR4(p_);
        float fy = (float)(kh < 64 ? kh : kh - 128) * (1.0f / 25.6f);
        float ph = -0.15707963267948966f * fy * fy;
        float ps, pcs; __sincosf(ph, &ps, &pcs);
        pytp[t] = (v2f){pcs * (1.0f / 16384.0f), ps * (1.0f / 16384.0f)};
    }

    const float sA = (c < 4) ? 1.0f : -1.0f;
    const float sB = (c & 2) ? -1.0f : 1.0f;
    const float sC = (c & 1) ? -1.0f : 1.0f;
    const v2f sAp = {sA, sA}, sBp = {sB, sB}, sCp = {sC, sC};
    const v2f fA  = {FA_RE[c], FA_IM[c]};
    const v2f rrf = ((c & 3) == 3) ? (v2f){0.0f, -1.0f} : (v2f){1.0f, 0.0f};
    const v2f W1 = W1C, W2 = W2C, W3 = W3C;

    float fx = (float)(g < 64 ? g : g - 128) * (1.0f / 25.6f);
    float phx = -0.15707963267948966f * fx * fx;
    float pxs, pxc; __sincosf(phx, &pxs, &pxc);
    const v2f px = {pxc, pxs};

    const long long base = (long long)n * NPIX;
    const int a1w = rho_g ^ rc;                    // T1-write minor (BUF0)
    const int a1r = g * LSTR + (c ^ gh);           // T1-read base   (BUF0)
    const int a2w = BUF1 + (rho_g ^ c);            // T2-write minor (BUF1)
    const int a2r = BUF1 + g * LSTR + (rc ^ gh);   // T2-read base   (BUF1)

    v2f v[16];

    for (int m = 0; m < NMODES; m++) {
        // mode-top barrier: covers table init (m=0) and final-T1 WAR (m>0)
        __syncthreads();
        #pragma unroll
        for (int i = 0; i < 16; i++) {           // ex = probe[m]*patch(slice0)
            int w  = c + 8 * i;
            int pi = m * NPIX + g * 128 + w;
            v2f pr = {probe_re[pi], probe_im[pi]};
            int oi = (Y0 + g) * OBJW + X0 + w;
            v2f ob = {obj_re[oi], obj_im[oi]};
            v[i] = pk_cmul(pr, ob);
        }

        for (int s = 1; s < NSLICES; s++) {
            pass_A_fwd(v, c, sAp, sBp, sCp, fA, rrf, W1, W2, W3, tA);
            #pragma unroll                       // T1 write -> BUF0
            for (int p = 0; p < 16; p++) {
                int kw = BR4(p) + 16 * rc;
                LTH[kw * LSTR + a1w] = toh2(v[p]);
            }
            __syncthreads();
            #pragma unroll                       // T1 read <- BUF0 (no WAR bar:
            for (int i = 0; i < 16; i++)         //  next BUF0 write is after the
                v[i] = frh2(LTH[a1r + 8 * i]);   //  T2 barrier below)
            pass_B_fwd(v, c, sAp, sBp, sCp, fA, rrf, W1, W2, W3, tB);
            #pragma unroll                       // * prop
            for (int p = 0; p < 16; p++) {
                v2f pp = pk_cmul(pytp[8 * p + c], px);
                v[p] = pk_cmul(v[p], pp);
            }
            pass_B_inv(v, c, sAp, sBp, sCp, fA, rrf, W1, W2, W3, tB);
            #pragma unroll                       // T2 write -> BUF1
            for (int i = 0; i < 16; i++)
                LTH[(i + 16 * c) * LSTR + a2w] = toh2(v[i]);
            __syncthreads();
            #pragma unroll                       // T2 read <- BUF1 (no WAR bar:
            for (int p = 0; p < 16; p++)         //  next BUF1 write is after the
                v[p] = frh2(LTH[a2r + 8 * BR4(p)]); // next T1 barrier)
            pass_A_inv(v, c, sAp, sBp, sCp, fA, rrf, W1, W2, W3, tA);
            #pragma unroll                       // * patch(slice s)
            for (int i = 0; i < 16; i++) {
                int w  = c + 8 * i;
                int oi = (s * OBJW + Y0 + g) * OBJW + X0 + w;
                v2f ob = {obj_re[oi], obj_im[oi]};
                v[i] = pk_cmul(v[i], ob);
            }
        }

        // final FFT2: Fw, T1(BUF0), Fh(pass_B), |.|^2 RMW into out
        pass_A_fwd(v, c, sAp, sBp, sCp, fA, rrf, W1, W2, W3, tA);
        #pragma unroll
        for (int p = 0; p < 16; p++) {
            int kw = BR4(p) + 16 * rc;
            LTH[kw * LSTR + a1w] = toh2(v[p]);
        }
        __syncthreads();
        #pragma unroll
        for (int i = 0; i < 16; i++)
            v[i] = frh2(LTH[a1r + 8 * i]);
        pass_B_fwd(v, c, sAp, sBp, sCp, fA, rrf, W1, W2, W3, tB);
        // fftshift: (kh,kw)->(kh^64,kw^64); kh=br3(c)+8BR4(p), kw=g.
        #pragma unroll
        for (int p = 0; p < 16; p++) {
            int kh = BR3(c) + 8 * BR4(p);
            long long oidx = base + (long long)(((kh ^ 64) << 7) + (g ^ 64));
            float val = fmaf(v[p].x, v[p].x, v[p].y * v[p].y);
            if (m > 0) val += out[oidx];
            out[oidx] = val;
        }
    }
}

extern "C" void kernel_launch(void* const* d_in, const int* in_sizes, int n_in,
                              void* d_out, int out_size, void* d_ws, size_t ws_size,
                              hipStream_t stream) {
    const float* probe_re = (const float*)d_in[0];
    const float* probe_im = (const float*)d_in[1];
    const float* obj_re   = (const float*)d_in[2];
    const float* obj_im   = (const float*)d_in[3];
    const int*   pos      = (const int*)d_in[4];
    float* out = (float*)d_out;

    const int N = out_size / NPIX;   // 512 positions
    multislice_kernel<<<dim3(N), dim3(NT), 0, stream>>>(
        probe_re, probe_im, obj_re, obj_im, pos, out);
}

// Round 7
// 1307.163 us; speedup vs baseline: 2.2756x; 1.8343x over previous
//
#include <hip/hip_runtime.h>
#include <hip/hip_fp16.h>
#include <math.h>

#define NT      1024
#define NPIX    16384
#define NSLICES 8
#define NMODES  4
#define OBJW    512
#define LSTR    136        // padded major stride (half2 units): 136%32=8
#define BUF1    (128 * LSTR)   // second transpose buffer offset (half2 units)

typedef float v2f __attribute__((ext_vector_type(2)));

// ---- packed fp32 complex primitives (VOP3P) --------------------------------
__device__ __forceinline__ v2f pk_add(v2f a, v2f b) {
    v2f d; asm("v_pk_add_f32 %0, %1, %2" : "=v"(d) : "v"(a), "v"(b)); return d;
}
__device__ __forceinline__ v2f pk_sub(v2f a, v2f b) {
    v2f d; asm("v_pk_add_f32 %0, %1, %2 neg_lo:[0,1] neg_hi:[0,1]"
               : "=v"(d) : "v"(a), "v"(b)); return d;
}
__device__ __forceinline__ v2f pk_fma(v2f a, v2f b, v2f c) {
    v2f d; asm("v_pk_fma_f32 %0, %1, %2, %3" : "=v"(d) : "v"(a), "v"(b), "v"(c)); return d;
}
// d = a*b (complex):  t=(ax*bx, ay*bx);  d=(t.x - ay*by, t.y + ax*by)
__device__ __forceinline__ v2f pk_cmul(v2f a, v2f b) {
    v2f t, d;
    asm("v_pk_mul_f32 %0, %1, %2 op_sel:[0,0] op_sel_hi:[1,0]"
        : "=v"(t) : "v"(a), "v"(b));
    asm("v_pk_fma_f32 %0, %1, %2, %3 op_sel:[1,1,0] op_sel_hi:[0,1,1] neg_lo:[1,0,0]"
        : "=v"(d) : "v"(a), "v"(b), "v"(t));
    return d;
}
// d = a*conj(b)
__device__ __forceinline__ v2f pk_cmulc(v2f a, v2f b) {
    v2f t, d;
    asm("v_pk_mul_f32 %0, %1, %2 op_sel:[0,0] op_sel_hi:[1,0]"
        : "=v"(t) : "v"(a), "v"(b));
    asm("v_pk_fma_f32 %0, %1, %2, %3 op_sel:[1,1,0] op_sel_hi:[0,1,1] neg_hi:[1,0,0]"
        : "=v"(d) : "v"(a), "v"(b), "v"(t));
    return d;
}
__device__ __forceinline__ v2f pk_mnegi(v2f a) { return (v2f){a.y, -a.x}; }  // a * -i
__device__ __forceinline__ v2f pk_mposi(v2f a) { return (v2f){-a.y, a.x}; }  // a * +i

// 4-bit reversal (constexpr -> folds to literals in unrolled loops)
__host__ __device__ constexpr int BR4(int p) {
    return ((p & 1) << 3) | ((p & 2) << 1) | ((p & 4) >> 1) | ((p & 8) >> 3);
}
__host__ __device__ constexpr int BR3(int c) {
    return ((c & 1) << 2) | (c & 2) | ((c & 4) >> 2);
}

// ---- lane exchange primitives ---------------------------------------------
__device__ __forceinline__ float xor1f(float x) {
    int i = __float_as_int(x);
    return __int_as_float(__builtin_amdgcn_update_dpp(i, i, 0xB1, 0xF, 0xF, false));
}
__device__ __forceinline__ float xor2f(float x) {
    int i = __float_as_int(x);
    return __int_as_float(__builtin_amdgcn_update_dpp(i, i, 0x4E, 0xF, 0xF, false));
}
__device__ __forceinline__ float xor4f(float x) {
    return __int_as_float(__builtin_amdgcn_ds_swizzle(__float_as_int(x), 0x101F));
}

// cross-8 stage-A twiddle fA(c) = (c<4) ? 1 : W8^(c-4)
__device__ __constant__ float FA_RE[8] = {1,1,1,1, 1.0f,  0.707106781f,  0.0f, -0.707106781f};
__device__ __constant__ float FA_IM[8] = {0,0,0,0, 0.0f, -0.707106781f, -1.0f, -0.707106781f};

// ---- local 16-point FFT in registers (packed, r2-proven codegen) -----------
// W[k] = (cos, sin) of 2*pi*k/16 -- const array, constant-indexed after unroll
__device__ __forceinline__ void fft16_fwd(v2f v[16], const v2f* W) {
    #pragma unroll
    for (int s = 8; s >= 1; s >>= 1) {
        #pragma unroll
        for (int q = 0; q < 16; q += 2 * s) {
            #pragma unroll
            for (int j = 0; j < s; j++) {
                const int tw = j * (8 / s);
                v2f u = v[q + j], w = v[q + j + s];
                v[q + j] = pk_add(u, w);
                v2f d = pk_sub(u, w);
                v[q + j + s] = (tw == 0) ? d
                             : (tw == 4) ? pk_mnegi(d)
                                         : pk_cmulc(d, W[tw]);
            }
        }
    }
}
__device__ __forceinline__ void fft16_inv(v2f v[16], const v2f* W) {
    #pragma unroll
    for (int s = 1; s <= 8; s <<= 1) {
        #pragma unroll
        for (int q = 0; q < 16; q += 2 * s) {
            #pragma unroll
            for (int j = 0; j < s; j++) {
                const int tw = j * (8 / s);
                v2f u = v[q + j], w = v[q + j + s];
                v2f tv = (tw == 0) ? w
                       : (tw == 4) ? pk_mposi(w)
                                   : pk_cmul(w, W[tw]);
                v[q + j]     = pk_add(u, tv);
                v[q + j + s] = pk_sub(u, tv);
            }
        }
    }
}

// ---- cross-thread DFT8 over sub-index c (xor 4,2,1) ------------------------
__device__ __forceinline__ void cross8_fwd(v2f v[16], v2f sAp, v2f sBp, v2f sCp,
                                           v2f fA, v2f rrf) {
    #pragma unroll
    for (int p = 0; p < 16; p++) {
        v2f o;
        o.x = xor4f(v[p].x); o.y = xor4f(v[p].y);
        v2f a = pk_fma(sAp, v[p], o);
        v2f b = pk_cmul(a, fA);
        o.x = xor2f(b.x); o.y = xor2f(b.y);
        v2f n = pk_fma(sBp, b, o);
        v2f r = pk_cmul(n, rrf);
        o.x = xor1f(r.x); o.y = xor1f(r.y);
        v[p] = pk_fma(sCp, r, o);
    }
}
__device__ __forceinline__ void cross8_inv(v2f v[16], v2f sAp, v2f sBp, v2f sCp,
                                           v2f fA, v2f rrf) {
    #pragma unroll
    for (int p = 0; p < 16; p++) {
        v2f o;
        o.x = xor1f(v[p].x); o.y = xor1f(v[p].y);
        v2f n = pk_fma(sCp, v[p], o);
        v2f r = pk_cmulc(n, rrf);
        o.x = xor2f(r.x); o.y = xor2f(r.y);
        v2f b = pk_fma(sBp, r, o);
        v2f a = pk_cmulc(b, fA);
        o.x = xor4f(a.x); o.y = xor4f(a.y);
        v[p] = pk_fma(sAp, a, o);
    }
}

// ---- pass A (local-first): input reg i = elem c+8i; out reg p = BR4(p)+16rc
__device__ __forceinline__ void pass_A_fwd(v2f v[16], int c, v2f sAp, v2f sBp,
                                           v2f sCp, v2f fA, v2f rrf,
                                           const v2f* W, const v2f* tA) {
    fft16_fwd(v, W);
    #pragma unroll
    for (int p = 0; p < 16; p++) v[p] = pk_cmul(v[p], tA[8 * p + c]);
    cross8_fwd(v, sAp, sBp, sCp, fA, rrf);
}
__device__ __forceinline__ void pass_A_inv(v2f v[16], int c, v2f sAp, v2f sBp,
                                           v2f sCp, v2f fA, v2f rrf,
                                           const v2f* W, const v2f* tA) {
    cross8_inv(v, sAp, sBp, sCp, fA, rrf);
    #pragma unroll
    for (int p = 0; p < 16; p++) v[p] = pk_cmulc(v[p], tA[8 * p + c]);
    fft16_inv(v, W);
}

// ---- pass B (cross-first): input reg i = elem i+16c
__device__ __forceinline__ void pass_B_fwd(v2f v[16], int c, v2f sAp, v2f sBp,
                                           v2f sCp, v2f fA, v2f rrf,
                                           const v2f* W, const v2f* tB) {
    cross8_fwd(v, sAp, sBp, sCp, fA, rrf);
    #pragma unroll
    for (int i = 0; i < 16; i++) v[i] = pk_cmul(v[i], tB[8 * i + c]);
    fft16_fwd(v, W);
}
__device__ __forceinline__ void pass_B_inv(v2f v[16], int c, v2f sAp, v2f sBp,
                                           v2f sCp, v2f fA, v2f rrf,
                                           const v2f* W, const v2f* tB) {
    fft16_inv(v, W);
    #pragma unroll
    for (int i = 0; i < 16; i++) v[i] = pk_cmulc(v[i], tB[8 * i + c]);
    cross8_inv(v, sAp, sBp, sCp, fA, rrf);
}

// ---- conversions -----------------------------------------------------------
__device__ __forceinline__ __half2 toh2(v2f a) {
    return __float22half2_rn(make_float2(a.x, a.y));
}
__device__ __forceinline__ v2f frh2(__half2 h) {
    float2 f = __half22float2(h);
    return (v2f){f.x, f.y};
}

// ---- main kernel: r2 codegen + DOUBLE-BUFFERED transpose (2 bars/slice) ----
// T1 -> BUF0, T2 -> BUF1: each buffer's read->next-write WAR hazard is guarded
// by the OTHER transpose's barrier, so each transpose needs only one
// __syncthreads (write->bar->read). LDS = 2x69.6KB + 3KB tables = 142KB.
// Occupancy was already 1 WG/CU at 72KB (r2 measured 47%), so no residency loss.
__global__ void
__attribute__((amdgpu_flat_work_group_size(1024, 1024)))
multislice_kernel(const float* __restrict__ probe_re,
                  const float* __restrict__ probe_im,
                  const float* __restrict__ obj_re,
                  const float* __restrict__ obj_im,
                  const int*   __restrict__ positions,
                  float*       __restrict__ out)
{
    __shared__ __half2 LTH[2 * 128 * LSTR];   // 139264 B: BUF0 (T1) + BUF1 (T2)
    __shared__ v2f     tA[128];           // pass-A twiddle [8p+c]
    __shared__ v2f     tB[128];           // pass-B twiddle [8i+c]
    __shared__ v2f     pytp[128];         // prop y-factor/16384, kh=br3(c)+8BR4(p)

    const int t  = threadIdx.x;
    const int g  = t >> 3;                      // row (R) / col (C) index
    const int c  = t & 7;
    const int rc = BR3(c);
    const int gh = g >> 4;                      // sigma(g)
    const int rho_g = ((g & 15) << 3) | gh;     // rho(g)
    const int n  = blockIdx.x;
    const int Y0 = positions[2 * n];
    const int X0 = positions[2 * n + 1];

    if (t < 128) {
        int p_ = t >> 3, c_ = t & 7;
        float angA = -2.0f * 3.14159265358979323846f
                     * (float)(c_ * BR4(p_)) / 128.0f;
        float s, cc; __sincosf(angA, &s, &cc);
        tA[t] = (v2f){cc, s};
        float angB = -2.0f * 3.14159265358979323846f
                     * (float)(p_ * BR3(c_)) / 128.0f;
        __sincosf(angB, &s, &cc);
        tB[t] = (v2f){cc, s};
        int kh = BR3(c_) + 8 * BR4(p_);
        float fy = (float)(kh < 64 ? kh : kh - 128) * (1.0f / 25.6f);
        float ph = -0.15707963267948966f * fy * fy;
        float ps, pcs; __sincosf(ph, &ps, &pcs);
        pytp[t] = (v2f){pcs * (1.0f / 16384.0f), ps * (1.0f / 16384.0f)};
    }

    // per-thread constants for the cross-8 stages
    const float sA = (c < 4) ? 1.0f : -1.0f;
    const float sB = (c & 2) ? -1.0f : 1.0f;
    const float sC = (c & 1) ? -1.0f : 1.0f;
    const v2f sAp = {sA, sA}, sBp = {sB, sB}, sCp = {sC, sC};
    const v2f fA  = {FA_RE[c], FA_IM[c]};
    const v2f rrf = ((c & 3) == 3) ? (v2f){0.0f, -1.0f} : (v2f){1.0f, 0.0f};

    // W16 twiddle pairs (compile-time constants, r2-proven codegen)
    const v2f W[8] = {
        { 1.0f,         0.0f        },
        { 0.923879533f, 0.382683432f},
        { 0.707106781f, 0.707106781f},
        { 0.382683432f, 0.923879533f},
        { 0.0f,         1.0f        },
        {-0.382683432f, 0.923879533f},
        {-0.707106781f, 0.707106781f},
        {-0.923879533f, 0.382683432f},
    };

    float fx = (float)(g < 64 ? g : g - 128) * (1.0f / 25.6f);
    float phx = -0.15707963267948966f * fx * fx;
    float pxs, pxc; __sincosf(phx, &pxs, &pxc);
    const v2f px = {pxc, pxs};

    const long long base = (long long)n * NPIX;
    // precomputed transpose address bases (T1 in BUF0, T2 in BUF1)
    const int a1w = rho_g ^ rc;                    // T1-write minor
    const int a1r = g * LSTR + (c ^ gh);           // T1-read base (+ 8i)
    const int a2w = BUF1 + (rho_g ^ c);            // T2-write minor
    const int a2r = BUF1 + g * LSTR + (rc ^ gh);   // T2-read base (+ 8*BR4(p))

    v2f v[16];

    for (int m = 0; m < NMODES; m++) {
        // mode-top barrier: covers table init (m=0) and final-T1 WAR (m>0)
        __syncthreads();
        #pragma unroll
        for (int i = 0; i < 16; i++) {           // ex = probe[m]*patch(slice0)
            int w  = c + 8 * i;
            int pi = m * NPIX + g * 128 + w;
            v2f pr = {probe_re[pi], probe_im[pi]};
            int oi = (Y0 + g) * OBJW + X0 + w;
            v2f ob = {obj_re[oi], obj_im[oi]};
            v[i] = pk_cmul(pr, ob);
        }

        for (int s = 1; s < NSLICES; s++) {
            pass_A_fwd(v, c, sAp, sBp, sCp, fA, rrf, W, tA);
            #pragma unroll                       // T1 write -> BUF0
            for (int p = 0; p < 16; p++) {
                int kw = BR4(p) + 16 * rc;
                LTH[kw * LSTR + a1w] = toh2(v[p]);
            }
            __syncthreads();
            #pragma unroll                       // T1 read <- BUF0 (no WAR bar:
            for (int i = 0; i < 16; i++)         //  next BUF0 write is after the
                v[i] = frh2(LTH[a1r + 8 * i]);   //  T2 barrier below)
            pass_B_fwd(v, c, sAp, sBp, sCp, fA, rrf, W, tB);
            #pragma unroll                       // * prop
            for (int p = 0; p < 16; p++) {
                v2f pp = pk_cmul(pytp[8 * p + c], px);
                v[p] = pk_cmul(v[p], pp);
            }
            pass_B_inv(v, c, sAp, sBp, sCp, fA, rrf, W, tB);
            #pragma unroll                       // T2 write -> BUF1
            for (int i = 0; i < 16; i++)
                LTH[(i + 16 * c) * LSTR + a2w] = toh2(v[i]);
            __syncthreads();
            #pragma unroll                       // T2 read <- BUF1 (no WAR bar:
            for (int p = 0; p < 16; p++)         //  next BUF1 write is after the
                v[p] = frh2(LTH[a2r + 8 * BR4(p)]); // next T1 barrier)
            pass_A_inv(v, c, sAp, sBp, sCp, fA, rrf, W, tA);
            #pragma unroll                       // * patch(slice s)
            for (int i = 0; i < 16; i++) {
                int w  = c + 8 * i;
                int oi = (s * OBJW + Y0 + g) * OBJW + X0 + w;
                v2f ob = {obj_re[oi], obj_im[oi]};
                v[i] = pk_cmul(v[i], ob);
            }
        }

        // final FFT2: Fw, T1(BUF0), Fh(pass_B), |.|^2 RMW into out
        pass_A_fwd(v, c, sAp, sBp, sCp, fA, rrf, W, tA);
        #pragma unroll
        for (int p = 0; p < 16; p++) {
            int kw = BR4(p) + 16 * rc;
            LTH[kw * LSTR + a1w] = toh2(v[p]);
        }
        __syncthreads();
        #pragma unroll
        for (int i = 0; i < 16; i++)
            v[i] = frh2(LTH[a1r + 8 * i]);
        pass_B_fwd(v, c, sAp, sBp, sCp, fA, rrf, W, tB);
        // fftshift: (kh,kw)->(kh^64,kw^64); kh=br3(c)+8BR4(p), kw=g.
        #pragma unroll
        for (int p = 0; p < 16; p++) {
            int kh = BR3(c) + 8 * BR4(p);
            long long oidx = base + (long long)(((kh ^ 64) << 7) + (g ^ 64));
            float val = fmaf(v[p].x, v[p].x, v[p].y * v[p].y);
            if (m > 0) val += out[oidx];
            out[oidx] = val;
        }
    }
}

extern "C" void kernel_launch(void* const* d_in, const int* in_sizes, int n_in,
                              void* d_out, int out_size, void* d_ws, size_t ws_size,
                              hipStream_t stream) {
    const float* probe_re = (const float*)d_in[0];
    const float* probe_im = (const float*)d_in[1];
    const float* obj_re   = (const float*)d_in[2];
    const float* obj_im   = (const float*)d_in[3];
    const int*   pos      = (const int*)d_in[4];
    float* out = (float*)d_out;

    const int N = out_size / NPIX;   // 512 positions
    multislice_kernel<<<dim3(N), dim3(NT), 0, stream>>>(
        probe_re, probe_im, obj_re, obj_im, pos, out);
}

// Round 8
// 1296.107 us; speedup vs baseline: 2.2950x; 1.0085x over previous
//
#include <hip/hip_runtime.h>
#include <hip/hip_fp16.h>
#include <math.h>

#define NT      1024
#define NPIX    16384
#define NSLICES 8
#define NMODES  4
#define OBJW    512
#define LSTR    136        // padded major stride (half2 units): 136%32=8
#define BUF1    (128 * LSTR)   // mode-u transpose buffer offset (half2 units)

typedef float v2f __attribute__((ext_vector_type(2)));

// ---- packed fp32 complex primitives (VOP3P) --------------------------------
__device__ __forceinline__ v2f pk_add(v2f a, v2f b) {
    v2f d; asm("v_pk_add_f32 %0, %1, %2" : "=v"(d) : "v"(a), "v"(b)); return d;
}
__device__ __forceinline__ v2f pk_sub(v2f a, v2f b) {
    v2f d; asm("v_pk_add_f32 %0, %1, %2 neg_lo:[0,1] neg_hi:[0,1]"
               : "=v"(d) : "v"(a), "v"(b)); return d;
}
__device__ __forceinline__ v2f pk_fma(v2f a, v2f b, v2f c) {
    v2f d; asm("v_pk_fma_f32 %0, %1, %2, %3" : "=v"(d) : "v"(a), "v"(b), "v"(c)); return d;
}
// d = a*b (complex):  t=(ax*bx, ay*bx);  d=(t.x - ay*by, t.y + ax*by)
__device__ __forceinline__ v2f pk_cmul(v2f a, v2f b) {
    v2f t, d;
    asm("v_pk_mul_f32 %0, %1, %2 op_sel:[0,0] op_sel_hi:[1,0]"
        : "=v"(t) : "v"(a), "v"(b));
    asm("v_pk_fma_f32 %0, %1, %2, %3 op_sel:[1,1,0] op_sel_hi:[0,1,1] neg_lo:[1,0,0]"
        : "=v"(d) : "v"(a), "v"(b), "v"(t));
    return d;
}
// d = a*conj(b)
__device__ __forceinline__ v2f pk_cmulc(v2f a, v2f b) {
    v2f t, d;
    asm("v_pk_mul_f32 %0, %1, %2 op_sel:[0,0] op_sel_hi:[1,0]"
        : "=v"(t) : "v"(a), "v"(b));
    asm("v_pk_fma_f32 %0, %1, %2, %3 op_sel:[1,1,0] op_sel_hi:[0,1,1] neg_hi:[1,0,0]"
        : "=v"(d) : "v"(a), "v"(b), "v"(t));
    return d;
}
__device__ __forceinline__ v2f pk_mnegi(v2f a) { return (v2f){a.y, -a.x}; }  // a * -i
__device__ __forceinline__ v2f pk_mposi(v2f a) { return (v2f){-a.y, a.x}; }  // a * +i

// 4-bit reversal (constexpr -> folds to literals in unrolled loops)
__host__ __device__ constexpr int BR4(int p) {
    return ((p & 1) << 3) | ((p & 2) << 1) | ((p & 4) >> 1) | ((p & 8) >> 3);
}
__host__ __device__ constexpr int BR3(int c) {
    return ((c & 1) << 2) | (c & 2) | ((c & 4) >> 2);
}

// ---- lane exchange primitives ---------------------------------------------
__device__ __forceinline__ float xor1f(float x) {
    int i = __float_as_int(x);
    return __int_as_float(__builtin_amdgcn_update_dpp(i, i, 0xB1, 0xF, 0xF, false));
}
__device__ __forceinline__ float xor2f(float x) {
    int i = __float_as_int(x);
    return __int_as_float(__builtin_amdgcn_update_dpp(i, i, 0x4E, 0xF, 0xF, false));
}
__device__ __forceinline__ float xor4f(float x) {
    return __int_as_float(__builtin_amdgcn_ds_swizzle(__float_as_int(x), 0x101F));
}

// cross-8 stage-A twiddle fA(c) = (c<4) ? 1 : W8^(c-4)
__device__ __constant__ float FA_RE[8] = {1,1,1,1, 1.0f,  0.707106781f,  0.0f, -0.707106781f};
__device__ __constant__ float FA_IM[8] = {0,0,0,0, 0.0f, -0.707106781f, -1.0f, -0.707106781f};

// ---- local 16-point FFT in registers (r2-proven codegen) -------------------
__device__ __forceinline__ void fft16_fwd(v2f v[16], const v2f* W) {
    #pragma unroll
    for (int s = 8; s >= 1; s >>= 1) {
        #pragma unroll
        for (int q = 0; q < 16; q += 2 * s) {
            #pragma unroll
            for (int j = 0; j < s; j++) {
                const int tw = j * (8 / s);
                v2f u = v[q + j], w = v[q + j + s];
                v[q + j] = pk_add(u, w);
                v2f d = pk_sub(u, w);
                v[q + j + s] = (tw == 0) ? d
                             : (tw == 4) ? pk_mnegi(d)
                                         : pk_cmulc(d, W[tw]);
            }
        }
    }
}
__device__ __forceinline__ void fft16_inv(v2f v[16], const v2f* W) {
    #pragma unroll
    for (int s = 1; s <= 8; s <<= 1) {
        #pragma unroll
        for (int q = 0; q < 16; q += 2 * s) {
            #pragma unroll
            for (int j = 0; j < s; j++) {
                const int tw = j * (8 / s);
                v2f u = v[q + j], w = v[q + j + s];
                v2f tv = (tw == 0) ? w
                       : (tw == 4) ? pk_mposi(w)
                                   : pk_cmul(w, W[tw]);
                v[q + j]     = pk_add(u, tv);
                v[q + j + s] = pk_sub(u, tv);
            }
        }
    }
}

// ---- cross-thread DFT8, TWO register sets interleaved ----------------------
// (swizzle/DPP latency of one set hides under the other's FMAs)
__device__ __forceinline__ void cross8_fwd2(v2f v[16], v2f u[16],
                                            v2f sAp, v2f sBp, v2f sCp,
                                            v2f fA, v2f rrf) {
    #pragma unroll
    for (int p = 0; p < 16; p++) {
        v2f o, q;
        o.x = xor4f(v[p].x); o.y = xor4f(v[p].y);
        q.x = xor4f(u[p].x); q.y = xor4f(u[p].y);
        v2f a  = pk_fma(sAp, v[p], o);
        v2f a2 = pk_fma(sAp, u[p], q);
        v2f b  = pk_cmul(a,  fA);
        v2f b2 = pk_cmul(a2, fA);
        o.x = xor2f(b.x);  o.y = xor2f(b.y);
        q.x = xor2f(b2.x); q.y = xor2f(b2.y);
        v2f n  = pk_fma(sBp, b,  o);
        v2f n2 = pk_fma(sBp, b2, q);
        v2f r  = pk_cmul(n,  rrf);
        v2f r2 = pk_cmul(n2, rrf);
        o.x = xor1f(r.x);  o.y = xor1f(r.y);
        q.x = xor1f(r2.x); q.y = xor1f(r2.y);
        v[p] = pk_fma(sCp, r,  o);
        u[p] = pk_fma(sCp, r2, q);
    }
}
__device__ __forceinline__ void cross8_inv2(v2f v[16], v2f u[16],
                                            v2f sAp, v2f sBp, v2f sCp,
                                            v2f fA, v2f rrf) {
    #pragma unroll
    for (int p = 0; p < 16; p++) {
        v2f o, q;
        o.x = xor1f(v[p].x); o.y = xor1f(v[p].y);
        q.x = xor1f(u[p].x); q.y = xor1f(u[p].y);
        v2f n  = pk_fma(sCp, v[p], o);
        v2f n2 = pk_fma(sCp, u[p], q);
        v2f r  = pk_cmulc(n,  rrf);
        v2f r2 = pk_cmulc(n2, rrf);
        o.x = xor2f(r.x);  o.y = xor2f(r.y);
        q.x = xor2f(r2.x); q.y = xor2f(r2.y);
        v2f b  = pk_fma(sBp, r,  o);
        v2f b2 = pk_fma(sBp, r2, q);
        v2f a  = pk_cmulc(b,  fA);
        v2f a2 = pk_cmulc(b2, fA);
        o.x = xor4f(a.x);  o.y = xor4f(a.y);
        q.x = xor4f(a2.x); q.y = xor4f(a2.y);
        v[p] = pk_fma(sAp, a,  o);
        u[p] = pk_fma(sAp, a2, q);
    }
}

// ---- dual-mode passes: ONE table read serves both modes --------------------
__device__ __forceinline__ void pass_A_fwd2(v2f v[16], v2f u[16], int c,
                                            v2f sAp, v2f sBp, v2f sCp,
                                            v2f fA, v2f rrf,
                                            const v2f* W, const v2f* tA) {
    fft16_fwd(v, W); fft16_fwd(u, W);
    #pragma unroll
    for (int p = 0; p < 16; p++) {
        v2f w = tA[8 * p + c];
        v[p] = pk_cmul(v[p], w);
        u[p] = pk_cmul(u[p], w);
    }
    cross8_fwd2(v, u, sAp, sBp, sCp, fA, rrf);
}
__device__ __forceinline__ void pass_A_inv2(v2f v[16], v2f u[16], int c,
                                            v2f sAp, v2f sBp, v2f sCp,
                                            v2f fA, v2f rrf,
                                            const v2f* W, const v2f* tA) {
    cross8_inv2(v, u, sAp, sBp, sCp, fA, rrf);
    #pragma unroll
    for (int p = 0; p < 16; p++) {
        v2f w = tA[8 * p + c];
        v[p] = pk_cmulc(v[p], w);
        u[p] = pk_cmulc(u[p], w);
    }
    fft16_inv(v, W); fft16_inv(u, W);
}
__device__ __forceinline__ void pass_B_fwd2(v2f v[16], v2f u[16], int c,
                                            v2f sAp, v2f sBp, v2f sCp,
                                            v2f fA, v2f rrf,
                                            const v2f* W, const v2f* tB) {
    cross8_fwd2(v, u, sAp, sBp, sCp, fA, rrf);
    #pragma unroll
    for (int i = 0; i < 16; i++) {
        v2f w = tB[8 * i + c];
        v[i] = pk_cmul(v[i], w);
        u[i] = pk_cmul(u[i], w);
    }
    fft16_fwd(v, W); fft16_fwd(u, W);
}
__device__ __forceinline__ void pass_B_inv2(v2f v[16], v2f u[16], int c,
                                            v2f sAp, v2f sBp, v2f sCp,
                                            v2f fA, v2f rrf,
                                            const v2f* W, const v2f* tB) {
    fft16_inv(v, W); fft16_inv(u, W);
    #pragma unroll
    for (int i = 0; i < 16; i++) {
        v2f w = tB[8 * i + c];
        v[i] = pk_cmulc(v[i], w);
        u[i] = pk_cmulc(u[i], w);
    }
    cross8_inv2(v, u, sAp, sBp, sCp, fA, rrf);
}

// ---- conversions -----------------------------------------------------------
__device__ __forceinline__ __half2 toh2(v2f a) {
    return __float22half2_rn(make_float2(a.x, a.y));
}
__device__ __forceinline__ v2f frh2(__half2 h) {
    float2 f = __half22float2(h);
    return (v2f){f.x, f.y};
}

// ---- main kernel: 1024 threads, TWO MODES per pass -------------------------
// BUF0 = mode-v transpose buffer, BUF1 = mode-u. Per slice: 4 barriers serve
// TWO modes (2/mode-slice); tA/tB/pytp reads and patch loads amortize x2;
// out-RMW once per pair. waves_per_eu(2): empirical VGPR cap = 256/min = 128
// (r4: min4->64, r5: min2->128); demand ~110 -> no spill, 16 waves/CU kept.
__global__ void
__attribute__((amdgpu_flat_work_group_size(1024, 1024), amdgpu_waves_per_eu(2)))
multislice_kernel(const float* __restrict__ probe_re,
                  const float* __restrict__ probe_im,
                  const float* __restrict__ obj_re,
                  const float* __restrict__ obj_im,
                  const int*   __restrict__ positions,
                  float*       __restrict__ out)
{
    __shared__ __half2 LTH[2 * 128 * LSTR];   // 139264 B: BUF0(v) + BUF1(u)
    __shared__ v2f     tA[128];           // pass-A twiddle [8p+c]
    __shared__ v2f     tB[128];           // pass-B twiddle [8i+c]
    __shared__ v2f     pytp[128];         // prop y-factor/16384, kh=br3(c)+8BR4(p)

    const int t  = threadIdx.x;
    const int g  = t >> 3;
    const int c  = t & 7;
    const int rc = BR3(c);
    const int gh = g >> 4;
    const int rho_g = ((g & 15) << 3) | gh;
    const int n  = blockIdx.x;
    const int Y0 = positions[2 * n];
    const int X0 = positions[2 * n + 1];

    if (t < 128) {
        int p_ = t >> 3, c_ = t & 7;
        float angA = -2.0f * 3.14159265358979323846f
                     * (float)(c_ * BR4(p_)) / 128.0f;
        float s, cc; __sincosf(angA, &s, &cc);
        tA[t] = (v2f){cc, s};
        float angB = -2.0f * 3.14159265358979323846f
                     * (float)(p_ * BR3(c_)) / 128.0f;
        __sincosf(angB, &s, &cc);
        tB[t] = (v2f){cc, s};
        int kh = BR3(c_) + 8 * BR4(p_);
        float fy = (float)(kh < 64 ? kh : kh - 128) * (1.0f / 25.6f);
        float ph = -0.15707963267948966f * fy * fy;
        float ps, pcs; __sincosf(ph, &ps, &pcs);
        pytp[t] = (v2f){pcs * (1.0f / 16384.0f), ps * (1.0f / 16384.0f)};
    }

    const float sA = (c < 4) ? 1.0f : -1.0f;
    const float sB = (c & 2) ? -1.0f : 1.0f;
    const float sC = (c & 1) ? -1.0f : 1.0f;
    const v2f sAp = {sA, sA}, sBp = {sB, sB}, sCp = {sC, sC};
    const v2f fA  = {FA_RE[c], FA_IM[c]};
    const v2f rrf = ((c & 3) == 3) ? (v2f){0.0f, -1.0f} : (v2f){1.0f, 0.0f};

    const v2f W[8] = {
        { 1.0f,         0.0f        },
        { 0.923879533f, 0.382683432f},
        { 0.707106781f, 0.707106781f},
        { 0.382683432f, 0.923879533f},
        { 0.0f,         1.0f        },
        {-0.382683432f, 0.923879533f},
        {-0.707106781f, 0.707106781f},
        {-0.923879533f, 0.382683432f},
    };

    float fx = (float)(g < 64 ? g : g - 128) * (1.0f / 25.6f);
    float phx = -0.15707963267948966f * fx * fx;
    float pxs, pxc; __sincosf(phx, &pxs, &pxc);
    const v2f px = {pxc, pxs};
    __syncthreads();   // table init visible before any pass

    const long long base = (long long)n * NPIX;
    const int a1w = rho_g ^ rc;                    // T1-write minor (BUF0; +BUF1 for u)
    const int a1r = g * LSTR + (c ^ gh);           // T1-read base (+ 8i)
    const int a2w = rho_g ^ c;                     // T2-write minor
    const int a2r = g * LSTR + (rc ^ gh);          // T2-read base (+ 8*BR4(p))

    v2f v[16], u[16];

    for (int m = 0; m < NMODES; m += 2) {
        #pragma unroll
        for (int i = 0; i < 16; i++) {           // ex = probe[m|m+1]*patch(slice0)
            int w  = c + 8 * i;
            int oi = (Y0 + g) * OBJW + X0 + w;
            v2f ob = {obj_re[oi], obj_im[oi]};   // shared patch load
            int pi0 = m * NPIX + g * 128 + w;
            v2f pr0 = {probe_re[pi0], probe_im[pi0]};
            v[i] = pk_cmul(pr0, ob);
            int pi1 = (m + 1) * NPIX + g * 128 + w;
            v2f pr1 = {probe_re[pi1], probe_im[pi1]};
            u[i] = pk_cmul(pr1, ob);
        }

        for (int s = 1; s < NSLICES; s++) {
            pass_A_fwd2(v, u, c, sAp, sBp, sCp, fA, rrf, W, tA);
            __syncthreads();   // WAR: prior T2-reads / final-T1-reads done
            #pragma unroll                       // T1 write
            for (int p = 0; p < 16; p++) {
                int kw = BR4(p) + 16 * rc;
                LTH[kw * LSTR + a1w]        = toh2(v[p]);
                LTH[BUF1 + kw * LSTR + a1w] = toh2(u[p]);
            }
            __syncthreads();
            #pragma unroll                       // T1 read
            for (int i = 0; i < 16; i++) {
                v[i] = frh2(LTH[a1r + 8 * i]);
                u[i] = frh2(LTH[BUF1 + a1r + 8 * i]);
            }
            pass_B_fwd2(v, u, c, sAp, sBp, sCp, fA, rrf, W, tB);
            #pragma unroll                       // * prop (shared table read)
            for (int p = 0; p < 16; p++) {
                v2f pp = pk_cmul(pytp[8 * p + c], px);
                v[p] = pk_cmul(v[p], pp);
                u[p] = pk_cmul(u[p], pp);
            }
            pass_B_inv2(v, u, c, sAp, sBp, sCp, fA, rrf, W, tB);
            __syncthreads();   // WAR: all T1-reads done before T2 writes
            #pragma unroll                       // T2 write
            for (int i = 0; i < 16; i++) {
                LTH[(i + 16 * c) * LSTR + a2w]        = toh2(v[i]);
                LTH[BUF1 + (i + 16 * c) * LSTR + a2w] = toh2(u[i]);
            }
            __syncthreads();
            #pragma unroll                       // T2 read
            for (int p = 0; p < 16; p++) {
                v[p] = frh2(LTH[a2r + 8 * BR4(p)]);
                u[p] = frh2(LTH[BUF1 + a2r + 8 * BR4(p)]);
            }
            pass_A_inv2(v, u, c, sAp, sBp, sCp, fA, rrf, W, tA);
            #pragma unroll                       // * patch(slice s), shared load
            for (int i = 0; i < 16; i++) {
                int w  = c + 8 * i;
                int oi = (s * OBJW + Y0 + g) * OBJW + X0 + w;
                v2f ob = {obj_re[oi], obj_im[oi]};
                v[i] = pk_cmul(v[i], ob);
                u[i] = pk_cmul(u[i], ob);
            }
        }

        // final FFT2: Fw, T1, Fh(pass_B), |v|^2+|u|^2 RMW into out
        pass_A_fwd2(v, u, c, sAp, sBp, sCp, fA, rrf, W, tA);
        __syncthreads();   // WAR: slice-7 T2-reads done
        #pragma unroll
        for (int p = 0; p < 16; p++) {
            int kw = BR4(p) + 16 * rc;
            LTH[kw * LSTR + a1w]        = toh2(v[p]);
            LTH[BUF1 + kw * LSTR + a1w] = toh2(u[p]);
        }
        __syncthreads();
        #pragma unroll
        for (int i = 0; i < 16; i++) {
            v[i] = frh2(LTH[a1r + 8 * i]);
            u[i] = frh2(LTH[BUF1 + a1r + 8 * i]);
        }
        pass_B_fwd2(v, u, c, sAp, sBp, sCp, fA, rrf, W, tB);
        // fftshift: (kh,kw)->(kh^64,kw^64); kh=br3(c)+8BR4(p), kw=g.
        #pragma unroll
        for (int p = 0; p < 16; p++) {
            int kh = BR3(c) + 8 * BR4(p);
            long long oidx = base + (long long)(((kh ^ 64) << 7) + (g ^ 64));
            float val = fmaf(v[p].x, v[p].x, v[p].y * v[p].y);
            val = fmaf(u[p].x, u[p].x, fmaf(u[p].y, u[p].y, val));
            if (m > 0) val += out[oidx];
            out[oidx] = val;
        }
    }
}

extern "C" void kernel_launch(void* const* d_in, const int* in_sizes, int n_in,
                              void* d_out, int out_size, void* d_ws, size_t ws_size,
                              hipStream_t stream) {
    const float* probe_re = (const float*)d_in[0];
    const float* probe_im = (const float*)d_in[1];
    const float* obj_re   = (const float*)d_in[2];
    const float* obj_im   = (const float*)d_in[3];
    const int*   pos      = (const int*)d_in[4];
    float* out = (float*)d_out;

    const int N = out_size / NPIX;   // 512 positions
    multislice_kernel<<<dim3(N), dim3(NT), 0, stream>>>(
        probe_re, probe_im, obj_re, obj_im, pos, out);
}

// Round 9
// 1212.491 us; speedup vs baseline: 2.4533x; 1.0690x over previous
//
#include <hip/hip_runtime.h>
#include <hip/hip_fp16.h>
#include <math.h>

#define NT      1024
#define NPIX    16384
#define NSLICES 8
#define NMODES  4
#define OBJW    512
#define LSTR    136        // padded major stride (half2 units): 136%32=8

typedef float v2f __attribute__((ext_vector_type(2)));

// ---- packed fp32 complex primitives (VOP3P) --------------------------------
__device__ __forceinline__ v2f pk_add(v2f a, v2f b) {
    v2f d; asm("v_pk_add_f32 %0, %1, %2" : "=v"(d) : "v"(a), "v"(b)); return d;
}
__device__ __forceinline__ v2f pk_sub(v2f a, v2f b) {
    v2f d; asm("v_pk_add_f32 %0, %1, %2 neg_lo:[0,1] neg_hi:[0,1]"
               : "=v"(d) : "v"(a), "v"(b)); return d;
}
__device__ __forceinline__ v2f pk_fma(v2f a, v2f b, v2f c) {
    v2f d; asm("v_pk_fma_f32 %0, %1, %2, %3" : "=v"(d) : "v"(a), "v"(b), "v"(c)); return d;
}
// d = a*b (complex):  t=(ax*bx, ay*bx);  d=(t.x - ay*by, t.y + ax*by)
__device__ __forceinline__ v2f pk_cmul(v2f a, v2f b) {
    v2f t, d;
    asm("v_pk_mul_f32 %0, %1, %2 op_sel:[0,0] op_sel_hi:[1,0]"
        : "=v"(t) : "v"(a), "v"(b));
    asm("v_pk_fma_f32 %0, %1, %2, %3 op_sel:[1,1,0] op_sel_hi:[0,1,1] neg_lo:[1,0,0]"
        : "=v"(d) : "v"(a), "v"(b), "v"(t));
    return d;
}
// d = a*conj(b)
__device__ __forceinline__ v2f pk_cmulc(v2f a, v2f b) {
    v2f t, d;
    asm("v_pk_mul_f32 %0, %1, %2 op_sel:[0,0] op_sel_hi:[1,0]"
        : "=v"(t) : "v"(a), "v"(b));
    asm("v_pk_fma_f32 %0, %1, %2, %3 op_sel:[1,1,0] op_sel_hi:[0,1,1] neg_hi:[1,0,0]"
        : "=v"(d) : "v"(a), "v"(b), "v"(t));
    return d;
}
__device__ __forceinline__ v2f pk_mnegi(v2f a) { return (v2f){a.y, -a.x}; }  // a * -i
__device__ __forceinline__ v2f pk_mposi(v2f a) { return (v2f){-a.y, a.x}; }  // a * +i

// 4-bit reversal (constexpr -> folds to literals in unrolled loops)
__host__ __device__ constexpr int BR4(int p) {
    return ((p & 1) << 3) | ((p & 2) << 1) | ((p & 4) >> 1) | ((p & 8) >> 3);
}
__host__ __device__ constexpr int BR3(int c) {
    return ((c & 1) << 2) | (c & 2) | ((c & 4) >> 2);
}

// ---- lane exchange primitives: ALL DPP (full-rate VALU, zero LDS pipe) -----
// Affine relabel j<4->j, j>=4->11-j turns the DFT8 exchanges (4,2,1) into
// (7,2,1): xor7 = ROW_HALF_MIRROR (0x141), xor2/xor1 = quad_perm.
__device__ __forceinline__ float xor1f(float x) {
    int i = __float_as_int(x);
    return __int_as_float(__builtin_amdgcn_update_dpp(i, i, 0xB1, 0xF, 0xF, false));
}
__device__ __forceinline__ float xor2f(float x) {
    int i = __float_as_int(x);
    return __int_as_float(__builtin_amdgcn_update_dpp(i, i, 0x4E, 0xF, 0xF, false));
}
__device__ __forceinline__ float xor7f(float x) {
    int i = __float_as_int(x);
    return __int_as_float(__builtin_amdgcn_update_dpp(i, i, 0x141, 0xF, 0xF, false));
}

// relabeled stage-A twiddle fA'(lane) = lane<4 ? 1 : W8^(j(lane)-4) = W8^(7-lane)
__device__ __constant__ float FA2_RE[8] = {1,1,1,1, -0.707106781f,  0.0f, 0.707106781f, 1.0f};
__device__ __constant__ float FA2_IM[8] = {0,0,0,0, -0.707106781f, -1.0f,-0.707106781f, 0.0f};

// ---- local 16-point FFT in registers (r2-proven codegen) -------------------
__device__ __forceinline__ void fft16_fwd(v2f v[16], const v2f* W) {
    #pragma unroll
    for (int s = 8; s >= 1; s >>= 1) {
        #pragma unroll
        for (int q = 0; q < 16; q += 2 * s) {
            #pragma unroll
            for (int j = 0; j < s; j++) {
                const int tw = j * (8 / s);
                v2f u = v[q + j], w = v[q + j + s];
                v[q + j] = pk_add(u, w);
                v2f d = pk_sub(u, w);
                v[q + j + s] = (tw == 0) ? d
                             : (tw == 4) ? pk_mnegi(d)
                                         : pk_cmulc(d, W[tw]);
            }
        }
    }
}
__device__ __forceinline__ void fft16_inv(v2f v[16], const v2f* W) {
    #pragma unroll
    for (int s = 1; s <= 8; s <<= 1) {
        #pragma unroll
        for (int q = 0; q < 16; q += 2 * s) {
            #pragma unroll
            for (int j = 0; j < s; j++) {
                const int tw = j * (8 / s);
                v2f u = v[q + j], w = v[q + j + s];
                v2f tv = (tw == 0) ? w
                       : (tw == 4) ? pk_mposi(w)
                                   : pk_cmul(w, W[tw]);
                v[q + j]     = pk_add(u, tv);
                v[q + j + s] = pk_sub(u, tv);
            }
        }
    }
}

// ---- cross-thread DFT8 over logical j (exchanges xor7, xor2, xor1) ---------
// Lane l holds logical slot j(l) = l<4 ? l : 11-l. Constants are the
// phi-conjugates of the original network: sA by lane (j<4 <=> l<4), sB/sC/rot3
// by j(l), fA' = FA2. fwd: natural-j in, out at freq rcp=br3(j(l)).
__device__ __forceinline__ void cross8_fwd(v2f v[16], v2f sAp, v2f sBp, v2f sCp,
                                           v2f fA, v2f rrf) {
    #pragma unroll
    for (int p = 0; p < 16; p++) {
        v2f o;
        o.x = xor7f(v[p].x); o.y = xor7f(v[p].y);
        v2f a = pk_fma(sAp, v[p], o);
        v2f b = pk_cmul(a, fA);
        o.x = xor2f(b.x); o.y = xor2f(b.y);
        v2f n = pk_fma(sBp, b, o);
        v2f r = pk_cmul(n, rrf);
        o.x = xor1f(r.x); o.y = xor1f(r.y);
        v[p] = pk_fma(sCp, r, o);
    }
}
__device__ __forceinline__ void cross8_inv(v2f v[16], v2f sAp, v2f sBp, v2f sCp,
                                           v2f fA, v2f rrf) {
    #pragma unroll
    for (int p = 0; p < 16; p++) {
        v2f o;
        o.x = xor1f(v[p].x); o.y = xor1f(v[p].y);
        v2f n = pk_fma(sCp, v[p], o);
        v2f r = pk_cmulc(n, rrf);
        o.x = xor2f(r.x); o.y = xor2f(r.y);
        v2f b = pk_fma(sBp, r, o);
        v2f a = pk_cmulc(b, fA);
        o.x = xor7f(a.x); o.y = xor7f(a.y);
        v[p] = pk_fma(sAp, a, o);
    }
}

// ---- pass A (local-first): input reg i = elem jc+8i; out reg p = BR4(p)+16rcp
__device__ __forceinline__ void pass_A_fwd(v2f v[16], int c, v2f sAp, v2f sBp,
                                           v2f sCp, v2f fA, v2f rrf,
                                           const v2f* W, const v2f* tA) {
    fft16_fwd(v, W);
    #pragma unroll
    for (int p = 0; p < 16; p++) v[p] = pk_cmul(v[p], tA[8 * p + c]);
    cross8_fwd(v, sAp, sBp, sCp, fA, rrf);
}
__device__ __forceinline__ void pass_A_inv(v2f v[16], int c, v2f sAp, v2f sBp,
                                           v2f sCp, v2f fA, v2f rrf,
                                           const v2f* W, const v2f* tA) {
    cross8_inv(v, sAp, sBp, sCp, fA, rrf);
    #pragma unroll
    for (int p = 0; p < 16; p++) v[p] = pk_cmulc(v[p], tA[8 * p + c]);
    fft16_inv(v, W);
}

// ---- pass B (cross-first): input reg i = row i+16*jc
__device__ __forceinline__ void pass_B_fwd(v2f v[16], int c, v2f sAp, v2f sBp,
                                           v2f sCp, v2f fA, v2f rrf,
                                           const v2f* W, const v2f* tB) {
    cross8_fwd(v, sAp, sBp, sCp, fA, rrf);
    #pragma unroll
    for (int i = 0; i < 16; i++) v[i] = pk_cmul(v[i], tB[8 * i + c]);
    fft16_fwd(v, W);
}
__device__ __forceinline__ void pass_B_inv(v2f v[16], int c, v2f sAp, v2f sBp,
                                           v2f sCp, v2f fA, v2f rrf,
                                           const v2f* W, const v2f* tB) {
    fft16_inv(v, W);
    #pragma unroll
    for (int i = 0; i < 16; i++) v[i] = pk_cmulc(v[i], tB[8 * i + c]);
    cross8_inv(v, sAp, sBp, sCp, fA, rrf);
}

// ---- conversions -----------------------------------------------------------
__device__ __forceinline__ __half2 toh2(v2f a) {
    return __float22half2_rn(make_float2(a.x, a.y));
}
__device__ __forceinline__ v2f frh2(__half2 h) {
    float2 f = __half22float2(h);
    return (v2f){f.x, f.y};
}

// ---- main kernel: r2 structure + all-DPP cross8 (zero ds_swizzle) ----------
// Relabel map: jc = c<4 ? c : 11-c (logical sub-index), rcp = BR3(jc)
// (frequency sub-index). All tables/addresses re-baked with jc/rcp; per-wave
// LDS address multisets unchanged -> conflict-free layout preserved.
__global__ void
__attribute__((amdgpu_flat_work_group_size(1024, 1024)))
multislice_kernel(const float* __restrict__ probe_re,
                  const float* __restrict__ probe_im,
                  const float* __restrict__ obj_re,
                  const float* __restrict__ obj_im,
                  const int*   __restrict__ positions,
                  float*       __restrict__ out)
{
    __shared__ __half2 LTH[128 * LSTR];   // 69632 B transpose buffer (fp16)
    __shared__ v2f     tA[128];           // pass-A twiddle [8p+c], baked with jc
    __shared__ v2f     tB[128];           // pass-B twiddle [8i+c], baked with rcp
    __shared__ v2f     pytp[128];         // prop y-factor/16384, kh=rcp+8BR4(p)

    const int t  = threadIdx.x;
    const int g  = t >> 3;                      // row (R) / col (C) index
    const int c  = t & 7;
    const int jc  = (c < 4) ? c : 11 - c;       // logical sub-index this lane holds
    const int rcp = BR3(jc);                    // frequency sub-index after cross8
    const int gh = g >> 4;                      // sigma(g)
    const int rho_g = ((g & 15) << 3) | gh;     // rho(g)
    const int n  = blockIdx.x;
    const int Y0 = positions[2 * n];
    const int X0 = positions[2 * n + 1];

    if (t < 128) {
        int p_ = t >> 3, c_ = t & 7;
        int jc_  = (c_ < 4) ? c_ : 11 - c_;
        int rcp_ = BR3(jc_);
        float angA = -2.0f * 3.14159265358979323846f
                     * (float)(jc_ * BR4(p_)) / 128.0f;
        float s, cc; __sincosf(angA, &s, &cc);
        tA[t] = (v2f){cc, s};
        float angB = -2.0f * 3.14159265358979323846f
                     * (float)(p_ * rcp_) / 128.0f;
        __sincosf(angB, &s, &cc);
        tB[t] = (v2f){cc, s};
        int kh = rcp_ + 8 * BR4(p_);
        float fy = (float)(kh < 64 ? kh : kh - 128) * (1.0f / 25.6f);
        float ph = -0.15707963267948966f * fy * fy;
        float ps, pcs; __sincosf(ph, &ps, &pcs);
        pytp[t] = (v2f){pcs * (1.0f / 16384.0f), ps * (1.0f / 16384.0f)};
    }

    // per-lane constants for the relabeled cross-8 stages (phi-conjugates)
    const float sA = (c < 4) ? 1.0f : -1.0f;    // j<4 <=> lane<4
    const float sB = (jc & 2) ? -1.0f : 1.0f;
    const float sC = (jc & 1) ? -1.0f : 1.0f;
    const v2f sAp = {sA, sA}, sBp = {sB, sB}, sCp = {sC, sC};
    const v2f fA  = {FA2_RE[c], FA2_IM[c]};
    const v2f rrf = ((jc & 3) == 3) ? (v2f){0.0f, -1.0f} : (v2f){1.0f, 0.0f};

    // W16 twiddle pairs (compile-time constants, r2-proven codegen)
    const v2f W[8] = {
        { 1.0f,         0.0f        },
        { 0.923879533f, 0.382683432f},
        { 0.707106781f, 0.707106781f},
        { 0.382683432f, 0.923879533f},
        { 0.0f,         1.0f        },
        {-0.382683432f, 0.923879533f},
        {-0.707106781f, 0.707106781f},
        {-0.923879533f, 0.382683432f},
    };

    float fx = (float)(g < 64 ? g : g - 128) * (1.0f / 25.6f);
    float phx = -0.15707963267948966f * fx * fx;
    float pxs, pxc; __sincosf(phx, &pxs, &pxc);
    const v2f px = {pxc, pxs};
    __syncthreads();

    const long long base = (long long)n * NPIX;
    // precomputed transpose address bases (re-baked with jc/rcp)
    const int a1w = rho_g ^ rcp;                   // T1-write minor
    const int a1r = g * LSTR + (jc ^ gh);          // T1-read base (+ 8i)
    const int a2w = rho_g ^ jc;                    // T2-write minor
    const int a2r = g * LSTR + (rcp ^ gh);         // T2-read base (+ 8*BR4(p))

    v2f v[16];

    for (int m = 0; m < NMODES; m++) {
        __syncthreads();   // protect LTH reuse across modes
        #pragma unroll
        for (int i = 0; i < 16; i++) {           // ex = probe[m]*patch(slice0)
            int w  = jc + 8 * i;
            int pi = m * NPIX + g * 128 + w;
            v2f pr = {probe_re[pi], probe_im[pi]};
            int oi = (Y0 + g) * OBJW + X0 + w;
            v2f ob = {obj_re[oi], obj_im[oi]};
            v[i] = pk_cmul(pr, ob);
        }

        for (int s = 1; s < NSLICES; s++) {
            pass_A_fwd(v, c, sAp, sBp, sCp, fA, rrf, W, tA);
            #pragma unroll                       // T1 write [kw][r=g]
            for (int p = 0; p < 16; p++) {
                int kw = BR4(p) + 16 * rcp;
                LTH[kw * LSTR + a1w] = toh2(v[p]);
            }
            __syncthreads();
            #pragma unroll                       // T1 read -> C: reg i = row i+16jc
            for (int i = 0; i < 16; i++)
                v[i] = frh2(LTH[a1r + 8 * i]);
            __syncthreads();
            pass_B_fwd(v, c, sAp, sBp, sCp, fA, rrf, W, tB);
            #pragma unroll                       // * prop
            for (int p = 0; p < 16; p++) {
                v2f pp = pk_cmul(pytp[8 * p + c], px);
                v[p] = pk_cmul(v[p], pp);
            }
            pass_B_inv(v, c, sAp, sBp, sCp, fA, rrf, W, tB);
            #pragma unroll                       // T2 write [r=i+16jc][g]
            for (int i = 0; i < 16; i++)
                LTH[(i + 16 * jc) * LSTR + a2w] = toh2(v[i]);
            __syncthreads();
            #pragma unroll                       // T2 read -> R: reg p = kw
            for (int p = 0; p < 16; p++)
                v[p] = frh2(LTH[a2r + 8 * BR4(p)]);
            __syncthreads();
            pass_A_inv(v, c, sAp, sBp, sCp, fA, rrf, W, tA);
            #pragma unroll                       // * patch(slice s)
            for (int i = 0; i < 16; i++) {
                int w  = jc + 8 * i;
                int oi = (s * OBJW + Y0 + g) * OBJW + X0 + w;
                v2f ob = {obj_re[oi], obj_im[oi]};
                v[i] = pk_cmul(v[i], ob);
            }
        }

        // final FFT2: Fw, T1, Fh(pass_B), |.|^2 RMW into out
        pass_A_fwd(v, c, sAp, sBp, sCp, fA, rrf, W, tA);
        #pragma unroll
        for (int p = 0; p < 16; p++) {
            int kw = BR4(p) + 16 * rcp;
            LTH[kw * LSTR + a1w] = toh2(v[p]);
        }
        __syncthreads();
        #pragma unroll
        for (int i = 0; i < 16; i++)
            v[i] = frh2(LTH[a1r + 8 * i]);
        pass_B_fwd(v, c, sAp, sBp, sCp, fA, rrf, W, tB);
        // fftshift: (kh,kw)->(kh^64,kw^64); kh=rcp+8BR4(p), kw=g.
        // Same thread owns the same slots every mode -> plain RMW, no race.
        #pragma unroll
        for (int p = 0; p < 16; p++) {
            int kh = rcp + 8 * BR4(p);
            long long oidx = base + (long long)(((kh ^ 64) << 7) + (g ^ 64));
            float val = fmaf(v[p].x, v[p].x, v[p].y * v[p].y);
            if (m > 0) val += out[oidx];
            out[oidx] = val;
        }
    }
}

extern "C" void kernel_launch(void* const* d_in, const int* in_sizes, int n_in,
                              void* d_out, int out_size, void* d_ws, size_t ws_size,
                              hipStream_t stream) {
    const float* probe_re = (const float*)d_in[0];
    const float* probe_im = (const float*)d_in[1];
    const float* obj_re   = (const float*)d_in[2];
    const float* obj_im   = (const float*)d_in[3];
    const int*   pos      = (const int*)d_in[4];
    float* out = (float*)d_out;

    const int N = out_size / NPIX;   // 512 positions
    multislice_kernel<<<dim3(N), dim3(NT), 0, stream>>>(
        probe_re, probe_im, obj_re, obj_im, pos, out);
}